// Round 1
// baseline (3478.740 us; speedup 1.0000x reference)
//
#include <hip/hip_runtime.h>
#include <cstddef>
#include <cstdint>

#define NN 100000
#define NE 1600000
#define ET (NE + NN)
#define HALFN (NN / 2)
#define NEG_SLOPE 0.2f

// ---- order-preserving float<->uint for atomicMax on floats (incl. negatives) ----
__device__ __forceinline__ unsigned f2key(float f) {
  unsigned b = __float_as_uint(f);
  return (b & 0x80000000u) ? ~b : (b | 0x80000000u);
}
__device__ __forceinline__ float key2f(unsigned k) {
  unsigned b = (k & 0x80000000u) ? (k & 0x7fffffffu) : ~k;
  return __uint_as_float(b);
}
__device__ __forceinline__ float lrelu(float x) { return x > 0.f ? x : NEG_SLOPE * x; }

// ---------------- GEMM, M % 4 == 0: Y[n,M] = X[n,K] @ W[K,M] ----------------
template<int K, int M>
__launch_bounds__(256)
__global__ void gemm4_kernel(const float* __restrict__ X, const float* __restrict__ W,
                             float* __restrict__ Y, int n) {
  constexpr int CG = M / 4;        // column groups of 4
  constexpr int RG = 256 / CG;     // row groups
  constexpr int RPT = 2;           // rows per thread
  constexpr int RT = RG * RPT;     // rows per tile
  constexpr int KP = K + 1;        // pad to kill bank conflicts on sX
  __shared__ __align__(16) float sW[K * M];
  __shared__ float sX[RT * KP];
  for (int i = threadIdx.x; i < K * M; i += 256) sW[i] = W[i];
  const int jg = threadIdx.x % CG;
  const int rg = threadIdx.x / CG;
  const int r0 = rg * RPT;
  for (int base = blockIdx.x * RT; base < n; base += gridDim.x * RT) {
    __syncthreads();
    const int nrows = (n - base) < RT ? (n - base) : RT;
    for (int i = threadIdx.x; i < nrows * K; i += 256) {
      int r = i / K, c = i - r * K;
      sX[r * KP + c] = X[(size_t)base * K + i];
    }
    __syncthreads();
    float acc[RPT][4];
    #pragma unroll
    for (int rr = 0; rr < RPT; ++rr) acc[rr][0] = acc[rr][1] = acc[rr][2] = acc[rr][3] = 0.f;
    #pragma unroll 4
    for (int k = 0; k < K; ++k) {
      const float4 w = *(const float4*)&sW[k * M + jg * 4];
      #pragma unroll
      for (int rr = 0; rr < RPT; ++rr) {
        const float xv = sX[(r0 + rr) * KP + k];
        acc[rr][0] = fmaf(xv, w.x, acc[rr][0]);
        acc[rr][1] = fmaf(xv, w.y, acc[rr][1]);
        acc[rr][2] = fmaf(xv, w.z, acc[rr][2]);
        acc[rr][3] = fmaf(xv, w.w, acc[rr][3]);
      }
    }
    #pragma unroll
    for (int rr = 0; rr < RPT; ++rr) {
      if (r0 + rr < nrows) {
        float4 o = make_float4(acc[rr][0], acc[rr][1], acc[rr][2], acc[rr][3]);
        *(float4*)&Y[(size_t)(base + r0 + rr) * M + jg * 4] = o;
      }
    }
  }
}

// ---------------- GEMM, small M (M=2): simple per-output ----------------
template<int K, int M, int ROWS>
__launch_bounds__(256)
__global__ void gemm_s_kernel(const float* __restrict__ X, const float* __restrict__ W,
                              float* __restrict__ Y, int n) {
  constexpr int KP = K + 1;
  __shared__ float sW[K * M];
  __shared__ float sX[ROWS * KP];
  for (int i = threadIdx.x; i < K * M; i += 256) sW[i] = W[i];
  for (int base = blockIdx.x * ROWS; base < n; base += gridDim.x * ROWS) {
    __syncthreads();
    const int nrows = (n - base) < ROWS ? (n - base) : ROWS;
    for (int i = threadIdx.x; i < nrows * K; i += 256) {
      int r = i / K, c = i - r * K;
      sX[r * KP + c] = X[(size_t)base * K + i];
    }
    __syncthreads();
    for (int o = threadIdx.x; o < nrows * M; o += 256) {
      int r = o / M, j = o - r * M;
      float a = 0.f;
      #pragma unroll
      for (int k = 0; k < K; ++k) a = fmaf(sX[r * KP + k], sW[k * M + j], a);
      Y[(size_t)(base + r) * M + j] = a;
    }
  }
}

// ---------------- per-node per-head attention scores s,t ----------------
template<int H, int C>
__launch_bounds__(256)
__global__ void score_kernel(const float* __restrict__ Hm,
                             const float* __restrict__ aS, const float* __restrict__ aD,
                             float* __restrict__ S, float* __restrict__ T, int n) {
  int idx = blockIdx.x * 256 + threadIdx.x;
  if (idx >= n * H) return;
  int h = idx & (H - 1);
  const float* hp = Hm + (size_t)idx * C;  // node*H*C + h*C == idx*C
  float s = 0.f, t = 0.f;
  #pragma unroll
  for (int c = 0; c < C; ++c) {
    float v = hp[c];
    s = fmaf(v, aS[h * C + c], s);
    t = fmaf(v, aD[h * C + c], t);
  }
  S[idx] = s;
  T[idx] = t;
}

// ---------------- segment max of leaky_relu(s[src]+t[dst]) ----------------
template<int H>
__launch_bounds__(256)
__global__ void gat_max_kernel(const int* __restrict__ esrc, const int* __restrict__ edst,
                               const float* __restrict__ S, const float* __restrict__ T,
                               unsigned* __restrict__ MK) {
  int idx = blockIdx.x * 256 + threadIdx.x;
  if (idx >= ET * H) return;
  int e = idx / H, h = idx - e * H;
  int sn = e < NE ? esrc[e] : e - NE;
  int dn = e < NE ? edst[e] : e - NE;
  float ev = lrelu(S[sn * H + h] + T[dn * H + h]);
  atomicMax(&MK[dn * H + h], f2key(ev));
}

__launch_bounds__(256)
__global__ void key_to_float_kernel(unsigned* __restrict__ MK, int count) {
  int idx = blockIdx.x * 256 + threadIdx.x;
  if (idx >= count) return;
  unsigned k = MK[idx];
  float m = (k == 0u) ? 0.f : key2f(k);   // k==0: empty segment -> 0 (matches ref isfinite guard)
  ((float*)MK)[idx] = m;
}

// ---------------- segment sum of p = exp(e - m[dst]) ----------------
template<int H>
__launch_bounds__(256)
__global__ void gat_denom_kernel(const int* __restrict__ esrc, const int* __restrict__ edst,
                                 const float* __restrict__ S, const float* __restrict__ T,
                                 const float* __restrict__ M, float* __restrict__ Dn) {
  int idx = blockIdx.x * 256 + threadIdx.x;
  if (idx >= ET * H) return;
  int e = idx / H, h = idx - e * H;
  int sn = e < NE ? esrc[e] : e - NE;
  int dn = e < NE ? edst[e] : e - NE;
  float ev = lrelu(S[sn * H + h] + T[dn * H + h]);
  float p = __expf(ev - M[dn * H + h]);
  atomicAdd(&Dn[dn * H + h], p);
}

// ---------------- out[dst] += h[src] * alpha ----------------
template<int H, int C>
__launch_bounds__(256)
__global__ void gat_scatter_kernel(const int* __restrict__ esrc, const int* __restrict__ edst,
                                   const float* __restrict__ S, const float* __restrict__ T,
                                   const float* __restrict__ M, const float* __restrict__ Dn,
                                   const float* __restrict__ Hm, float* __restrict__ Out) {
  constexpr int F = H * C;
  int idx = blockIdx.x * 256 + threadIdx.x;
  if (idx >= (int)((long long)ET * F)) return;
  int e = idx / F, f = idx - e * F;
  int h = f / C;
  int sn = e < NE ? esrc[e] : e - NE;
  int dn = e < NE ? edst[e] : e - NE;
  float ev = lrelu(S[sn * H + h] + T[dn * H + h]);
  float alpha = __expf(ev - M[dn * H + h]) / (Dn[dn * H + h] + 1e-16f);
  atomicAdd(&Out[(size_t)dn * F + f], Hm[(size_t)sn * F + f] * alpha);
}

// ---------------- GCN helpers ----------------
__launch_bounds__(256)
__global__ void deg_kernel(const int* __restrict__ edst, float* __restrict__ deg) {
  int e = blockIdx.x * 256 + threadIdx.x;
  if (e >= ET) return;
  int dn = e < NE ? edst[e] : e - NE;
  atomicAdd(&deg[dn], 1.f);
}

__launch_bounds__(256)
__global__ void rsqrt_kernel(float* __restrict__ deg, int n) {
  int i = blockIdx.x * 256 + threadIdx.x;
  if (i >= n) return;
  float d = deg[i];
  deg[i] = d > 0.f ? rsqrtf(d) : 0.f;
}

__launch_bounds__(256)
__global__ void gcn_scatter_kernel(const int* __restrict__ esrc, const int* __restrict__ edst,
                                   const float* __restrict__ dinv,
                                   const float* __restrict__ Hm, float* __restrict__ Out) {
  int idx = blockIdx.x * 256 + threadIdx.x;
  if (idx >= ET * 16) return;
  int e = idx >> 4, c = idx & 15;
  int sn = e < NE ? esrc[e] : e - NE;
  int dn = e < NE ? edst[e] : e - NE;
  float norm = dinv[sn] * dinv[dn];
  atomicAdd(&Out[(size_t)dn * 16 + c], Hm[(size_t)sn * 16 + c] * norm);
}

// ---------------- bias + ELU (in place) ----------------
template<int F>
__launch_bounds__(256)
__global__ void bias_elu_kernel(float* __restrict__ A, const float* __restrict__ b, int n) {
  int idx = blockIdx.x * 256 + threadIdx.x;
  if (idx >= n * F) return;
  int f = idx & (F - 1);
  float v = A[idx] + b[f];
  A[idx] = v > 0.f ? v : expm1f(v);
}

// ---------------- final concat + log_softmax ----------------
__launch_bounds__(256)
__global__ void final_kernel(const float* __restrict__ A, float* __restrict__ Out) {
  int i = blockIdx.x * 256 + threadIdx.x;
  if (i >= HALFN) return;
  float v0 = A[(size_t)i * 2 + 0];
  float v1 = A[(size_t)i * 2 + 1];
  float v2 = A[(size_t)(i + HALFN) * 2 + 0];
  float v3 = A[(size_t)(i + HALFN) * 2 + 1];
  float m = fmaxf(fmaxf(v0, v1), fmaxf(v2, v3));
  float e0 = __expf(v0 - m), e1 = __expf(v1 - m), e2 = __expf(v2 - m), e3 = __expf(v3 - m);
  float l = logf(e0 + e1 + e2 + e3) + m;
  Out[(size_t)i * 4 + 0] = v0 - l;
  Out[(size_t)i * 4 + 1] = v1 - l;
  Out[(size_t)i * 4 + 2] = v2 - l;
  Out[(size_t)i * 4 + 3] = v3 - l;
}

// ---------------- one GAT layer ----------------
template<int K, int H, int C>
static void run_gat(const float* Xin, const float* W, const float* aS, const float* aD,
                    const float* bias, const int* esrc, const int* edst,
                    float* bufH, float* bufOut, float* S, float* T, float* Mb, float* Dn,
                    hipStream_t stream) {
  constexpr int F = H * C;
  if constexpr (F % 4 == 0) {
    constexpr int RT = (256 / (F / 4)) * 2;
    int tiles = (NN + RT - 1) / RT;
    if (tiles > 4096) tiles = 4096;
    gemm4_kernel<K, F><<<tiles, 256, 0, stream>>>(Xin, W, bufH, NN);
  } else {
    int tiles = (NN + 127) / 128;
    if (tiles > 2048) tiles = 2048;
    gemm_s_kernel<K, F, 128><<<tiles, 256, 0, stream>>>(Xin, W, bufH, NN);
  }
  score_kernel<H, C><<<(NN * H + 255) / 256, 256, 0, stream>>>(bufH, aS, aD, S, T, NN);
  hipMemsetAsync(Mb, 0, (size_t)NN * H * 4, stream);
  hipMemsetAsync(Dn, 0, (size_t)NN * H * 4, stream);
  hipMemsetAsync(bufOut, 0, (size_t)NN * F * 4, stream);
  gat_max_kernel<H><<<(ET * H + 255) / 256, 256, 0, stream>>>(esrc, edst, S, T, (unsigned*)Mb);
  key_to_float_kernel<<<(NN * H + 255) / 256, 256, 0, stream>>>((unsigned*)Mb, NN * H);
  gat_denom_kernel<H><<<(ET * H + 255) / 256, 256, 0, stream>>>(esrc, edst, S, T, Mb, Dn);
  {
    long long tot = (long long)ET * F;
    int blocks = (int)((tot + 255) / 256);
    gat_scatter_kernel<H, C><<<blocks, 256, 0, stream>>>(esrc, edst, S, T, Mb, Dn, bufH, bufOut);
  }
  bias_elu_kernel<F><<<(NN * F + 255) / 256, 256, 0, stream>>>(bufOut, bias, NN);
}

extern "C" void kernel_launch(void* const* d_in, const int* in_sizes, int n_in,
                              void* d_out, int out_size, void* d_ws, size_t ws_size,
                              hipStream_t stream) {
  const float* x     = (const float*)d_in[0];
  const int*   eidx  = (const int*)d_in[1];
  const int*   esrc  = eidx;
  const int*   edst  = eidx + NE;
  const float* gcn_w = (const float*)d_in[2];
  const float* gcn_b = (const float*)d_in[3];

  char* ws = (char*)d_ws;
  float* bufA = (float*)(ws + 0);            // N*128 f32  (layer I/O, accumulators)
  float* bufB = (float*)(ws + 51200000);     // N*128 f32  (post-GEMM h)
  float* Sb   = (float*)(ws + 102400000);    // N*8
  float* Tb   = (float*)(ws + 105600000);    // N*8
  float* Mb   = (float*)(ws + 108800000);    // N*8 (uint keys then float max)
  float* Dnb  = (float*)(ws + 112000000);    // N*8
  float* degb = (float*)(ws + 115200000);    // N

  // ---------------- GCN layer: x[n,128] -> bufA[n,16] ----------------
  {
    constexpr int RT = (256 / (16 / 4)) * 2;  // 128 rows/tile
    int tiles = (NN + RT - 1) / RT;
    if (tiles > 4096) tiles = 4096;
    gemm4_kernel<128, 16><<<tiles, 256, 0, stream>>>(x, gcn_w, bufB, NN);
  }
  hipMemsetAsync(degb, 0, (size_t)NN * 4, stream);
  hipMemsetAsync(bufA, 0, (size_t)NN * 16 * 4, stream);
  deg_kernel<<<(ET + 255) / 256, 256, 0, stream>>>(edst, degb);
  rsqrt_kernel<<<(NN + 255) / 256, 256, 0, stream>>>(degb, NN);
  gcn_scatter_kernel<<<(ET * 16 + 255) / 256, 256, 0, stream>>>(esrc, edst, degb, bufB, bufA);
  bias_elu_kernel<16><<<(NN * 16 + 255) / 256, 256, 0, stream>>>(bufA, gcn_b, NN);

  // ---------------- GAT layers ----------------
  // g1: 16 -> (8,16)
  run_gat<16, 8, 16>(bufA, (const float*)d_in[4], (const float*)d_in[5], (const float*)d_in[6],
                     (const float*)d_in[7], esrc, edst, bufB, bufA, Sb, Tb, Mb, Dnb, stream);
  // g2: 128 -> (8,16)
  run_gat<128, 8, 16>(bufA, (const float*)d_in[8], (const float*)d_in[9], (const float*)d_in[10],
                      (const float*)d_in[11], esrc, edst, bufB, bufA, Sb, Tb, Mb, Dnb, stream);
  // g3: 128 -> (8,16)
  run_gat<128, 8, 16>(bufA, (const float*)d_in[12], (const float*)d_in[13], (const float*)d_in[14],
                      (const float*)d_in[15], esrc, edst, bufB, bufA, Sb, Tb, Mb, Dnb, stream);
  // g4: 128 -> (1,2)
  run_gat<128, 1, 2>(bufA, (const float*)d_in[16], (const float*)d_in[17], (const float*)d_in[18],
                     (const float*)d_in[19], esrc, edst, bufB, bufA, Sb, Tb, Mb, Dnb, stream);

  // ---------------- concat + log_softmax -> d_out [HALFN,4] ----------------
  final_kernel<<<(HALFN + 255) / 256, 256, 0, stream>>>(bufA, (float*)d_out);
}

// Round 2
// 1612.913 us; speedup vs baseline: 2.1568x; 2.1568x over previous
//
#include <hip/hip_runtime.h>
#include <cstddef>
#include <cstdint>

#define NN 100000
#define NE 1600000
#define ET (NE + NN)
#define HALFN (NN / 2)
#define NEG_SLOPE 0.2f
#define SCB 1024   // elements per scan block

__device__ __forceinline__ float lrelu(float x) { return x > 0.f ? x : NEG_SLOPE * x; }

// ---------------- GEMM, M % 4 == 0: Y[n,M] = X[n,K] @ W[K,M] ----------------
template<int K, int M>
__launch_bounds__(256)
__global__ void gemm4_kernel(const float* __restrict__ X, const float* __restrict__ W,
                             float* __restrict__ Y, int n) {
  constexpr int CG = M / 4;        // column groups of 4
  constexpr int RG = 256 / CG;     // row groups
  constexpr int RPT = 2;           // rows per thread
  constexpr int RT = RG * RPT;     // rows per tile
  constexpr int KP = K + 1;        // pad to kill bank conflicts on sX
  __shared__ __align__(16) float sW[K * M];
  __shared__ float sX[RT * KP];
  for (int i = threadIdx.x; i < K * M; i += 256) sW[i] = W[i];
  const int jg = threadIdx.x % CG;
  const int rg = threadIdx.x / CG;
  const int r0 = rg * RPT;
  for (int base = blockIdx.x * RT; base < n; base += gridDim.x * RT) {
    __syncthreads();
    const int nrows = (n - base) < RT ? (n - base) : RT;
    for (int i = threadIdx.x; i < nrows * K; i += 256) {
      int r = i / K, c = i - r * K;
      sX[r * KP + c] = X[(size_t)base * K + i];
    }
    __syncthreads();
    float acc[RPT][4];
    #pragma unroll
    for (int rr = 0; rr < RPT; ++rr) acc[rr][0] = acc[rr][1] = acc[rr][2] = acc[rr][3] = 0.f;
    #pragma unroll 4
    for (int k = 0; k < K; ++k) {
      const float4 w = *(const float4*)&sW[k * M + jg * 4];
      #pragma unroll
      for (int rr = 0; rr < RPT; ++rr) {
        const float xv = sX[(r0 + rr) * KP + k];
        acc[rr][0] = fmaf(xv, w.x, acc[rr][0]);
        acc[rr][1] = fmaf(xv, w.y, acc[rr][1]);
        acc[rr][2] = fmaf(xv, w.z, acc[rr][2]);
        acc[rr][3] = fmaf(xv, w.w, acc[rr][3]);
      }
    }
    #pragma unroll
    for (int rr = 0; rr < RPT; ++rr) {
      if (r0 + rr < nrows) {
        float4 o = make_float4(acc[rr][0], acc[rr][1], acc[rr][2], acc[rr][3]);
        *(float4*)&Y[(size_t)(base + r0 + rr) * M + jg * 4] = o;
      }
    }
  }
}

// ---------------- GEMM, small M (M=2) ----------------
template<int K, int M, int ROWS>
__launch_bounds__(256)
__global__ void gemm_s_kernel(const float* __restrict__ X, const float* __restrict__ W,
                              float* __restrict__ Y, int n) {
  constexpr int KP = K + 1;
  __shared__ float sW[K * M];
  __shared__ float sX[ROWS * KP];
  for (int i = threadIdx.x; i < K * M; i += 256) sW[i] = W[i];
  for (int base = blockIdx.x * ROWS; base < n; base += gridDim.x * ROWS) {
    __syncthreads();
    const int nrows = (n - base) < ROWS ? (n - base) : ROWS;
    for (int i = threadIdx.x; i < nrows * K; i += 256) {
      int r = i / K, c = i - r * K;
      sX[r * KP + c] = X[(size_t)base * K + i];
    }
    __syncthreads();
    for (int o = threadIdx.x; o < nrows * M; o += 256) {
      int r = o / M, j = o - r * M;
      float a = 0.f;
      #pragma unroll
      for (int k = 0; k < K; ++k) a = fmaf(sX[r * KP + k], sW[k * M + j], a);
      Y[(size_t)(base + r) * M + j] = a;
    }
  }
}

// ---------------- per-node per-head attention scores s,t ----------------
template<int H, int C>
__launch_bounds__(256)
__global__ void score_kernel(const float* __restrict__ Hm,
                             const float* __restrict__ aS, const float* __restrict__ aD,
                             float* __restrict__ S, float* __restrict__ T, int n) {
  int idx = blockIdx.x * 256 + threadIdx.x;
  if (idx >= n * H) return;
  int h = idx & (H - 1);
  const float* hp = Hm + (size_t)idx * C;
  float s = 0.f, t = 0.f;
  #pragma unroll
  for (int c = 0; c < C; ++c) {
    float v = hp[c];
    s = fmaf(v, aS[h * C + c], s);
    t = fmaf(v, aD[h * C + c], t);
  }
  S[idx] = s;
  T[idx] = t;
}

// ================= CSR build (counting sort by dst) =================
__launch_bounds__(256)
__global__ void deg_int_kernel(const int* __restrict__ edst, int* __restrict__ degi) {
  int e = blockIdx.x * 256 + threadIdx.x;
  if (e >= ET) return;
  int dn = e < NE ? edst[e] : e - NE;
  atomicAdd(&degi[dn], 1);
}

__launch_bounds__(256)
__global__ void scan1_kernel(const int* __restrict__ degi, int* __restrict__ rowptr,
                             int* __restrict__ bsums) {
  __shared__ int sd[256];
  int t = threadIdx.x;
  int base = blockIdx.x * SCB + t * 4;
  int v0 = base + 0 < NN ? degi[base + 0] : 0;
  int v1 = base + 1 < NN ? degi[base + 1] : 0;
  int v2 = base + 2 < NN ? degi[base + 2] : 0;
  int v3 = base + 3 < NN ? degi[base + 3] : 0;
  int s = v0 + v1 + v2 + v3;
  sd[t] = s;
  __syncthreads();
  for (int off = 1; off < 256; off <<= 1) {
    int x = (t >= off) ? sd[t - off] : 0;
    __syncthreads();
    sd[t] += x;
    __syncthreads();
  }
  int excl = sd[t] - s;
  if (t == 255) bsums[blockIdx.x] = sd[255];
  if (base + 0 < NN) rowptr[base + 0] = excl;
  excl += v0;
  if (base + 1 < NN) rowptr[base + 1] = excl;
  excl += v1;
  if (base + 2 < NN) rowptr[base + 2] = excl;
  excl += v2;
  if (base + 3 < NN) rowptr[base + 3] = excl;
}

__launch_bounds__(256)
__global__ void scan2_kernel(int* __restrict__ bsums, int nb) {
  __shared__ int sd[256];
  int t = threadIdx.x;
  int v = t < nb ? bsums[t] : 0;
  sd[t] = v;
  __syncthreads();
  for (int off = 1; off < 256; off <<= 1) {
    int x = (t >= off) ? sd[t - off] : 0;
    __syncthreads();
    sd[t] += x;
    __syncthreads();
  }
  if (t < nb) bsums[t] = sd[t] - v;  // exclusive
}

__launch_bounds__(256)
__global__ void scan3_kernel(int* __restrict__ rowptr, const int* __restrict__ bsums,
                             float* __restrict__ dinv_unused) {
  int i = blockIdx.x * 256 + threadIdx.x;
  if (i < NN) rowptr[i] += bsums[i / SCB];
  if (i == 0) rowptr[NN] = ET;
}

__launch_bounds__(256)
__global__ void dinv_kernel(const int* __restrict__ rowptr, float* __restrict__ dinv) {
  int i = blockIdx.x * 256 + threadIdx.x;
  if (i >= NN) return;
  int d = rowptr[i + 1] - rowptr[i];
  dinv[i] = d > 0 ? rsqrtf((float)d) : 0.f;
}

__launch_bounds__(256)
__global__ void fill_kernel(const int* __restrict__ esrc, const int* __restrict__ edst,
                            const int* __restrict__ rowptr, int* __restrict__ cursor,
                            int* __restrict__ csr_src) {
  int e = blockIdx.x * 256 + threadIdx.x;
  if (e >= ET) return;
  int dn = e < NE ? edst[e] : e - NE;
  int sn = e < NE ? esrc[e] : e - NE;
  int slot = rowptr[dn] + atomicAdd(&cursor[dn], 1);
  csr_src[slot] = sn;
}

// ================= pull-based GAT attention (no atomics) =================
// one 64-lane wave per dst node; lane = (slot-group, head)
template<int H>
__launch_bounds__(256)
__global__ void attn_kernel(const int* __restrict__ rowptr, const int* __restrict__ csr_src,
                            const float* __restrict__ S, const float* __restrict__ T,
                            float* __restrict__ alpha) {
  constexpr int NG = 64 / H;
  int wid = (blockIdx.x * 256 + threadIdx.x) >> 6;  // node (wave-uniform)
  if (wid >= NN) return;
  int lane = threadIdx.x & 63;
  int h = lane & (H - 1);
  int g = lane / H;
  int rs = rowptr[wid], re = rowptr[wid + 1];
  float Th = T[(size_t)wid * H + h];
  float m = -1e30f;
  for (int j = rs + g; j < re; j += NG) {
    int sn = csr_src[j];
    float e = lrelu(S[(size_t)sn * H + h] + Th);
    alpha[(size_t)j * H + h] = e;             // stash raw e (coalesced, CSR order)
    m = fmaxf(m, e);
  }
  #pragma unroll
  for (int mask = H; mask < 64; mask <<= 1) m = fmaxf(m, __shfl_xor(m, mask));
  float sum = 0.f;
  for (int j = rs + g; j < re; j += NG)
    sum += __expf(alpha[(size_t)j * H + h] - m);
  #pragma unroll
  for (int mask = H; mask < 64; mask <<= 1) sum += __shfl_xor(sum, mask);
  float inv = 1.f / (sum + 1e-16f);
  for (int j = rs + g; j < re; j += NG)
    alpha[(size_t)j * H + h] = __expf(alpha[(size_t)j * H + h] - m) * inv;
}

// ================= pull-based aggregation: out[d] = sum alpha * h[src] ========
template<int H, int C>
__launch_bounds__(256)
__global__ void pull_kernel(const int* __restrict__ rowptr, const int* __restrict__ csr_src,
                            const float* __restrict__ alpha, const float* __restrict__ Hm,
                            const float* __restrict__ bias, float* __restrict__ Out) {
  constexpr int F = H * C;
  constexpr int NPB = 256 / F;
  int d = blockIdx.x * NPB + threadIdx.x / F;
  if (d >= NN) return;
  int f = threadIdx.x & (F - 1);
  int h = f / C;
  int rs = rowptr[d], re = rowptr[d + 1];
  float acc = 0.f;
  int j = rs;
  if (j < re) {
    int sn = csr_src[j];
    float a = alpha[(size_t)j * H + h];
    for (; j + 1 < re; ++j) {
      int sn2 = csr_src[j + 1];
      float a2 = alpha[(size_t)(j + 1) * H + h];
      acc = fmaf(a, Hm[(size_t)sn * F + f], acc);
      sn = sn2; a = a2;
    }
    acc = fmaf(a, Hm[(size_t)sn * F + f], acc);
  }
  float v = acc + bias[f];
  Out[(size_t)d * F + f] = v > 0.f ? v : expm1f(v);
}

// ================= pull-based GCN =================
__launch_bounds__(256)
__global__ void gcn_pull_kernel(const int* __restrict__ rowptr, const int* __restrict__ csr_src,
                                const float* __restrict__ dinv, const float* __restrict__ Hm,
                                const float* __restrict__ bias, float* __restrict__ Out) {
  int d = blockIdx.x * 16 + threadIdx.x / 16;
  if (d >= NN) return;
  int f = threadIdx.x & 15;
  int rs = rowptr[d], re = rowptr[d + 1];
  float acc = 0.f;
  for (int j = rs; j < re; ++j) {
    int sn = csr_src[j];
    acc = fmaf(dinv[sn], Hm[(size_t)sn * 16 + f], acc);
  }
  float v = acc * dinv[d] + bias[f];
  Out[(size_t)d * 16 + f] = v > 0.f ? v : expm1f(v);
}

// ---------------- final concat + log_softmax ----------------
__launch_bounds__(256)
__global__ void final_kernel(const float* __restrict__ A, float* __restrict__ Out) {
  int i = blockIdx.x * 256 + threadIdx.x;
  if (i >= HALFN) return;
  float v0 = A[(size_t)i * 2 + 0];
  float v1 = A[(size_t)i * 2 + 1];
  float v2 = A[(size_t)(i + HALFN) * 2 + 0];
  float v3 = A[(size_t)(i + HALFN) * 2 + 1];
  float m = fmaxf(fmaxf(v0, v1), fmaxf(v2, v3));
  float e0 = __expf(v0 - m), e1 = __expf(v1 - m), e2 = __expf(v2 - m), e3 = __expf(v3 - m);
  float l = logf(e0 + e1 + e2 + e3) + m;
  Out[(size_t)i * 4 + 0] = v0 - l;
  Out[(size_t)i * 4 + 1] = v1 - l;
  Out[(size_t)i * 4 + 2] = v2 - l;
  Out[(size_t)i * 4 + 3] = v3 - l;
}

// ---------------- one GAT layer ----------------
template<int K, int H, int C>
static void run_gat(const float* Xin, const float* W, const float* aS, const float* aD,
                    const float* bias, const int* rowptr, const int* csr_src,
                    float* bufH, float* bufOut, float* S, float* T, float* alpha,
                    hipStream_t stream) {
  constexpr int F = H * C;
  if constexpr (F % 4 == 0) {
    constexpr int RT = (256 / (F / 4)) * 2;
    int tiles = (NN + RT - 1) / RT;
    if (tiles > 4096) tiles = 4096;
    gemm4_kernel<K, F><<<tiles, 256, 0, stream>>>(Xin, W, bufH, NN);
  } else {
    int tiles = (NN + 127) / 128;
    if (tiles > 2048) tiles = 2048;
    gemm_s_kernel<K, F, 128><<<tiles, 256, 0, stream>>>(Xin, W, bufH, NN);
  }
  score_kernel<H, C><<<(NN * H + 255) / 256, 256, 0, stream>>>(bufH, aS, aD, S, T, NN);
  attn_kernel<H><<<(NN * 64 + 255) / 256, 256, 0, stream>>>(rowptr, csr_src, S, T, alpha);
  {
    constexpr int NPB = 256 / F;
    pull_kernel<H, C><<<(NN + NPB - 1) / NPB, 256, 0, stream>>>(rowptr, csr_src, alpha, bufH,
                                                                bias, bufOut);
  }
}

extern "C" void kernel_launch(void* const* d_in, const int* in_sizes, int n_in,
                              void* d_out, int out_size, void* d_ws, size_t ws_size,
                              hipStream_t stream) {
  const float* x     = (const float*)d_in[0];
  const int*   eidx  = (const int*)d_in[1];
  const int*   esrc  = eidx;
  const int*   edst  = eidx + NE;
  const float* gcn_w = (const float*)d_in[2];
  const float* gcn_b = (const float*)d_in[3];

  char* ws = (char*)d_ws;
  float* bufA   = (float*)(ws + 0);            // N*128 f32
  float* bufB   = (float*)(ws + 51200000);     // N*128 f32
  float* Sb     = (float*)(ws + 102400000);    // N*8
  float* Tb     = (float*)(ws + 105600000);    // N*8
  float* alpha  = (float*)(ws + 108800000);    // ET*8 f32 (CSR order)
  int*   rowptr = (int*)  (ws + 163200128);    // NN+1
  int*   cursor = (int*)  (ws + 163600256);    // NN (also degi)
  int*   csr    = (int*)  (ws + 164000384);    // ET (src per CSR slot)
  float* dinv   = (float*)(ws + 170800384);    // NN
  int*   bsums  = (int*)  (ws + 171200512);    // ~98

  constexpr int NB_SCAN = (NN + SCB - 1) / SCB;  // 98

  // ---------------- CSR build ----------------
  hipMemsetAsync(cursor, 0, (size_t)NN * 4, stream);
  deg_int_kernel<<<(ET + 255) / 256, 256, 0, stream>>>(edst, cursor);
  scan1_kernel<<<NB_SCAN, 256, 0, stream>>>(cursor, rowptr, bsums);
  scan2_kernel<<<1, 256, 0, stream>>>(bsums, NB_SCAN);
  scan3_kernel<<<(NN + 256) / 256, 256, 0, stream>>>(rowptr, bsums, nullptr);
  dinv_kernel<<<(NN + 255) / 256, 256, 0, stream>>>(rowptr, dinv);
  hipMemsetAsync(cursor, 0, (size_t)NN * 4, stream);
  fill_kernel<<<(ET + 255) / 256, 256, 0, stream>>>(esrc, edst, rowptr, cursor, csr);

  // ---------------- GCN layer: x[n,128] -> bufA[n,16] ----------------
  {
    constexpr int RT = (256 / (16 / 4)) * 2;  // 128 rows/tile
    int tiles = (NN + RT - 1) / RT;
    if (tiles > 4096) tiles = 4096;
    gemm4_kernel<128, 16><<<tiles, 256, 0, stream>>>(x, gcn_w, bufB, NN);
  }
  gcn_pull_kernel<<<(NN + 15) / 16, 256, 0, stream>>>(rowptr, csr, dinv, bufB, gcn_b, bufA);

  // ---------------- GAT layers ----------------
  run_gat<16, 8, 16>(bufA, (const float*)d_in[4], (const float*)d_in[5], (const float*)d_in[6],
                     (const float*)d_in[7], rowptr, csr, bufB, bufA, Sb, Tb, alpha, stream);
  run_gat<128, 8, 16>(bufA, (const float*)d_in[8], (const float*)d_in[9], (const float*)d_in[10],
                      (const float*)d_in[11], rowptr, csr, bufB, bufA, Sb, Tb, alpha, stream);
  run_gat<128, 8, 16>(bufA, (const float*)d_in[12], (const float*)d_in[13], (const float*)d_in[14],
                      (const float*)d_in[15], rowptr, csr, bufB, bufA, Sb, Tb, alpha, stream);
  run_gat<128, 1, 2>(bufA, (const float*)d_in[16], (const float*)d_in[17], (const float*)d_in[18],
                     (const float*)d_in[19], rowptr, csr, bufB, bufA, Sb, Tb, alpha, stream);

  // ---------------- concat + log_softmax -> d_out [HALFN,4] ----------------
  final_kernel<<<(HALFN + 255) / 256, 256, 0, stream>>>(bufA, (float*)d_out);
}

// Round 3
// 809.280 us; speedup vs baseline: 4.2986x; 1.9930x over previous
//
#include <hip/hip_runtime.h>
#include <cstddef>
#include <cstdint>

#define NN 100000
#define NE 1600000
#define ET (NE + NN)
#define HALFN (NN / 2)
#define NEG_SLOPE 0.2f
#define SCB 1024   // elements per scan block

__device__ __forceinline__ float lrelu(float x) { return x > 0.f ? x : NEG_SLOPE * x; }

// ---- bf16 helpers (RNE pack, cheap unpack of a u32 holding 2 bf16) ----
__device__ __forceinline__ uint16_t f2bf(float f) {
  uint32_t u = __float_as_uint(f);
  uint32_t r = u + 0x7fffu + ((u >> 16) & 1u);
  return (uint16_t)(r >> 16);
}
__device__ __forceinline__ float bflo(uint32_t u) { return __uint_as_float(u << 16); }
__device__ __forceinline__ float bfhi(uint32_t u) { return __uint_as_float(u & 0xffff0000u); }

// ---------------- GEMM (f32 out), M % 4 == 0 ----------------
template<int K, int M>
__launch_bounds__(256)
__global__ void gemm4_kernel(const float* __restrict__ X, const float* __restrict__ W,
                             float* __restrict__ Y, int n) {
  constexpr int CG = M / 4;
  constexpr int RG = 256 / CG;
  constexpr int RPT = 2;
  constexpr int RT = RG * RPT;
  constexpr int KP = K + 1;
  __shared__ __align__(16) float sW[K * M];
  __shared__ float sX[RT * KP];
  for (int i = threadIdx.x; i < K * M; i += 256) sW[i] = W[i];
  const int jg = threadIdx.x % CG;
  const int rg = threadIdx.x / CG;
  const int r0 = rg * RPT;
  for (int base = blockIdx.x * RT; base < n; base += gridDim.x * RT) {
    __syncthreads();
    const int nrows = (n - base) < RT ? (n - base) : RT;
    for (int i = threadIdx.x; i < nrows * K; i += 256) {
      int r = i / K, c = i - r * K;
      sX[r * KP + c] = X[(size_t)base * K + i];
    }
    __syncthreads();
    float acc[RPT][4];
    #pragma unroll
    for (int rr = 0; rr < RPT; ++rr) acc[rr][0] = acc[rr][1] = acc[rr][2] = acc[rr][3] = 0.f;
    #pragma unroll 4
    for (int k = 0; k < K; ++k) {
      const float4 w = *(const float4*)&sW[k * M + jg * 4];
      #pragma unroll
      for (int rr = 0; rr < RPT; ++rr) {
        const float xv = sX[(r0 + rr) * KP + k];
        acc[rr][0] = fmaf(xv, w.x, acc[rr][0]);
        acc[rr][1] = fmaf(xv, w.y, acc[rr][1]);
        acc[rr][2] = fmaf(xv, w.z, acc[rr][2]);
        acc[rr][3] = fmaf(xv, w.w, acc[rr][3]);
      }
    }
    #pragma unroll
    for (int rr = 0; rr < RPT; ++rr) {
      if (r0 + rr < nrows) {
        float4 o = make_float4(acc[rr][0], acc[rr][1], acc[rr][2], acc[rr][3]);
        *(float4*)&Y[(size_t)(base + r0 + rr) * M + jg * 4] = o;
      }
    }
  }
}

// ---------------- GEMM M=128, bf16 output, two 64-col halves ----------------
template<int K>
__launch_bounds__(256)
__global__ void gemm_bf16_kernel(const float* __restrict__ X, const float* __restrict__ W,
                                 uint16_t* __restrict__ Y, int n) {
  constexpr int M = 128;
  constexpr int KP = K + 4;                 // keep 16B alignment of rows, stagger banks
  __shared__ __align__(16) float sW[K * 64];
  __shared__ __align__(16) float sX[64 * KP];
  const int jg = threadIdx.x & 15;          // 16 col-groups x 4 cols = 64
  const int rg = threadIdx.x >> 4;          // 16 row-groups x 4 rows = 64
  for (int base = blockIdx.x * 64; base < n; base += gridDim.x * 64) {
    __syncthreads();                        // protect sX vs previous tile readers
    const int nrows = (n - base) < 64 ? (n - base) : 64;
    for (int i = threadIdx.x; i < nrows * (K / 4); i += 256) {
      int r = i / (K / 4), c = i - r * (K / 4);
      float4 v = *(const float4*)&X[(size_t)(base + r) * K + c * 4];
      *(float4*)&sX[r * KP + c * 4] = v;
    }
    #pragma unroll
    for (int mh = 0; mh < 2; ++mh) {
      __syncthreads();                      // sX ready (mh=0) / prev half done (mh=1)
      for (int i = threadIdx.x; i < K * 16; i += 256) {
        int k = i >> 4, c = i & 15;
        float4 v = *(const float4*)&W[(size_t)k * M + mh * 64 + c * 4];
        *(float4*)&sW[k * 64 + c * 4] = v;
      }
      __syncthreads();                      // sW ready
      float acc[4][4];
      #pragma unroll
      for (int rr = 0; rr < 4; ++rr)
        acc[rr][0] = acc[rr][1] = acc[rr][2] = acc[rr][3] = 0.f;
      for (int k0 = 0; k0 < K; k0 += 4) {
        float xr[4][4];
        #pragma unroll
        for (int rr = 0; rr < 4; ++rr) {
          float4 v = *(const float4*)&sX[(rg * 4 + rr) * KP + k0];
          xr[rr][0] = v.x; xr[rr][1] = v.y; xr[rr][2] = v.z; xr[rr][3] = v.w;
        }
        #pragma unroll
        for (int kk = 0; kk < 4; ++kk) {
          const float4 w = *(const float4*)&sW[(k0 + kk) * 64 + jg * 4];
          #pragma unroll
          for (int rr = 0; rr < 4; ++rr) {
            acc[rr][0] = fmaf(xr[rr][kk], w.x, acc[rr][0]);
            acc[rr][1] = fmaf(xr[rr][kk], w.y, acc[rr][1]);
            acc[rr][2] = fmaf(xr[rr][kk], w.z, acc[rr][2]);
            acc[rr][3] = fmaf(xr[rr][kk], w.w, acc[rr][3]);
          }
        }
      }
      #pragma unroll
      for (int rr = 0; rr < 4; ++rr) {
        int r = rg * 4 + rr;
        if (r < nrows) {
          ushort4 p;
          p.x = f2bf(acc[rr][0]); p.y = f2bf(acc[rr][1]);
          p.z = f2bf(acc[rr][2]); p.w = f2bf(acc[rr][3]);
          *(ushort4*)&Y[(size_t)(base + r) * M + mh * 64 + jg * 4] = p;
        }
      }
    }
  }
}

// ---------------- GEMM, small M (M=2), f32 ----------------
template<int K, int M, int ROWS>
__launch_bounds__(256)
__global__ void gemm_s_kernel(const float* __restrict__ X, const float* __restrict__ W,
                              float* __restrict__ Y, int n) {
  constexpr int KP = K + 1;
  __shared__ float sW[K * M];
  __shared__ float sX[ROWS * KP];
  for (int i = threadIdx.x; i < K * M; i += 256) sW[i] = W[i];
  for (int base = blockIdx.x * ROWS; base < n; base += gridDim.x * ROWS) {
    __syncthreads();
    const int nrows = (n - base) < ROWS ? (n - base) : ROWS;
    for (int i = threadIdx.x; i < nrows * K; i += 256) {
      int r = i / K, c = i - r * K;
      sX[r * KP + c] = X[(size_t)base * K + i];
    }
    __syncthreads();
    for (int o = threadIdx.x; o < nrows * M; o += 256) {
      int r = o / M, j = o - r * M;
      float a = 0.f;
      #pragma unroll
      for (int k = 0; k < K; ++k) a = fmaf(sX[r * KP + k], sW[k * M + j], a);
      Y[(size_t)(base + r) * M + j] = a;
    }
  }
}

// ---------------- scores from bf16 h ----------------
template<int H, int C>
__launch_bounds__(256)
__global__ void score_bf16_kernel(const uint32_t* __restrict__ Hm,
                                  const float* __restrict__ aS, const float* __restrict__ aD,
                                  float* __restrict__ S, float* __restrict__ T, int n) {
  int idx = blockIdx.x * 256 + threadIdx.x;
  if (idx >= n * H) return;
  int h = idx & (H - 1);
  const uint32_t* hp = Hm + (size_t)idx * (C / 2);
  float s = 0.f, t = 0.f;
  #pragma unroll
  for (int c2 = 0; c2 < C / 2; ++c2) {
    uint32_t u = hp[c2];
    float v0 = bflo(u), v1 = bfhi(u);
    s = fmaf(v0, aS[h * C + 2 * c2], s);
    s = fmaf(v1, aS[h * C + 2 * c2 + 1], s);
    t = fmaf(v0, aD[h * C + 2 * c2], t);
    t = fmaf(v1, aD[h * C + 2 * c2 + 1], t);
  }
  S[idx] = s;
  T[idx] = t;
}

// ---------------- scores from f32 h (g4) ----------------
template<int H, int C>
__launch_bounds__(256)
__global__ void score_kernel(const float* __restrict__ Hm,
                             const float* __restrict__ aS, const float* __restrict__ aD,
                             float* __restrict__ S, float* __restrict__ T, int n) {
  int idx = blockIdx.x * 256 + threadIdx.x;
  if (idx >= n * H) return;
  int h = idx & (H - 1);
  const float* hp = Hm + (size_t)idx * C;
  float s = 0.f, t = 0.f;
  #pragma unroll
  for (int c = 0; c < C; ++c) {
    float v = hp[c];
    s = fmaf(v, aS[h * C + c], s);
    t = fmaf(v, aD[h * C + c], t);
  }
  S[idx] = s;
  T[idx] = t;
}

// ================= CSR build (counting sort by dst) =================
__launch_bounds__(256)
__global__ void deg_int_kernel(const int* __restrict__ edst, int* __restrict__ degi) {
  int e = blockIdx.x * 256 + threadIdx.x;
  if (e >= ET) return;
  int dn = e < NE ? edst[e] : e - NE;
  atomicAdd(&degi[dn], 1);
}

__launch_bounds__(256)
__global__ void scan1_kernel(const int* __restrict__ degi, int* __restrict__ rowptr,
                             int* __restrict__ bsums) {
  __shared__ int sd[256];
  int t = threadIdx.x;
  int base = blockIdx.x * SCB + t * 4;
  int v0 = base + 0 < NN ? degi[base + 0] : 0;
  int v1 = base + 1 < NN ? degi[base + 1] : 0;
  int v2 = base + 2 < NN ? degi[base + 2] : 0;
  int v3 = base + 3 < NN ? degi[base + 3] : 0;
  int s = v0 + v1 + v2 + v3;
  sd[t] = s;
  __syncthreads();
  for (int off = 1; off < 256; off <<= 1) {
    int x = (t >= off) ? sd[t - off] : 0;
    __syncthreads();
    sd[t] += x;
    __syncthreads();
  }
  int excl = sd[t] - s;
  if (t == 255) bsums[blockIdx.x] = sd[255];
  if (base + 0 < NN) rowptr[base + 0] = excl;
  excl += v0;
  if (base + 1 < NN) rowptr[base + 1] = excl;
  excl += v1;
  if (base + 2 < NN) rowptr[base + 2] = excl;
  excl += v2;
  if (base + 3 < NN) rowptr[base + 3] = excl;
}

__launch_bounds__(256)
__global__ void scan2_kernel(int* __restrict__ bsums, int nb) {
  __shared__ int sd[256];
  int t = threadIdx.x;
  int v = t < nb ? bsums[t] : 0;
  sd[t] = v;
  __syncthreads();
  for (int off = 1; off < 256; off <<= 1) {
    int x = (t >= off) ? sd[t - off] : 0;
    __syncthreads();
    sd[t] += x;
    __syncthreads();
  }
  if (t < nb) bsums[t] = sd[t] - v;  // exclusive
}

__launch_bounds__(256)
__global__ void scan3_kernel(int* __restrict__ rowptr, const int* __restrict__ bsums) {
  int i = blockIdx.x * 256 + threadIdx.x;
  if (i < NN) rowptr[i] += bsums[i / SCB];
  if (i == 0) rowptr[NN] = ET;
}

__launch_bounds__(256)
__global__ void dinv_kernel(const int* __restrict__ rowptr, float* __restrict__ dinv) {
  int i = blockIdx.x * 256 + threadIdx.x;
  if (i >= NN) return;
  int d = rowptr[i + 1] - rowptr[i];
  dinv[i] = d > 0 ? rsqrtf((float)d) : 0.f;
}

__launch_bounds__(256)
__global__ void fill_kernel(const int* __restrict__ esrc, const int* __restrict__ edst,
                            const int* __restrict__ rowptr, int* __restrict__ cursor,
                            int* __restrict__ csr_src) {
  int e = blockIdx.x * 256 + threadIdx.x;
  if (e >= ET) return;
  int dn = e < NE ? edst[e] : e - NE;
  int sn = e < NE ? esrc[e] : e - NE;
  int slot = rowptr[dn] + atomicAdd(&cursor[dn], 1);
  csr_src[slot] = sn;
}

// ================= attention v2: e cached in registers =================
// one 64-lane wave per dst node; lane = (slot-group g, head h); 4 slots/lane cached
template<int H>
__launch_bounds__(256)
__global__ void attn_kernel(const int* __restrict__ rowptr, const int* __restrict__ csr_src,
                            const float* __restrict__ S, const float* __restrict__ T,
                            float* __restrict__ alpha) {
  constexpr int NG = 64 / H;
  int wid = (blockIdx.x * 256 + threadIdx.x) >> 6;
  if (wid >= NN) return;
  int lane = threadIdx.x & 63;
  int h = lane & (H - 1);
  int g = lane / H;
  int rs = rowptr[wid], re = rowptr[wid + 1];
  float Th = T[(size_t)wid * H + h];
  int j0 = rs + g;
  float e0 = -1e30f, e1 = -1e30f, e2 = -1e30f, e3 = -1e30f;
  if (j0 < re)          e0 = lrelu(S[(size_t)csr_src[j0] * H + h] + Th);
  if (j0 + NG < re)     e1 = lrelu(S[(size_t)csr_src[j0 + NG] * H + h] + Th);
  if (j0 + 2 * NG < re) e2 = lrelu(S[(size_t)csr_src[j0 + 2 * NG] * H + h] + Th);
  if (j0 + 3 * NG < re) e3 = lrelu(S[(size_t)csr_src[j0 + 3 * NG] * H + h] + Th);
  float m = fmaxf(fmaxf(e0, e1), fmaxf(e2, e3));
  for (int j = j0 + 4 * NG; j < re; j += NG) {      // rare overflow: stash raw e
    float e = lrelu(S[(size_t)csr_src[j] * H + h] + Th);
    alpha[(size_t)j * H + h] = e;
    m = fmaxf(m, e);
  }
  #pragma unroll
  for (int mask = H; mask < 64; mask <<= 1) m = fmaxf(m, __shfl_xor(m, mask));
  float sum = __expf(e0 - m) + __expf(e1 - m) + __expf(e2 - m) + __expf(e3 - m);
  for (int j = j0 + 4 * NG; j < re; j += NG)
    sum += __expf(alpha[(size_t)j * H + h] - m);
  #pragma unroll
  for (int mask = H; mask < 64; mask <<= 1) sum += __shfl_xor(sum, mask);
  float inv = 1.f / (sum + 1e-16f);
  if (j0 < re)          alpha[(size_t)j0 * H + h]            = __expf(e0 - m) * inv;
  if (j0 + NG < re)     alpha[(size_t)(j0 + NG) * H + h]     = __expf(e1 - m) * inv;
  if (j0 + 2 * NG < re) alpha[(size_t)(j0 + 2 * NG) * H + h] = __expf(e2 - m) * inv;
  if (j0 + 3 * NG < re) alpha[(size_t)(j0 + 3 * NG) * H + h] = __expf(e3 - m) * inv;
  for (int j = j0 + 4 * NG; j < re; j += NG)
    alpha[(size_t)j * H + h] = __expf(alpha[(size_t)j * H + h] - m) * inv;
}

// ================= pull (bf16 h): one wave per node, 4-edge unroll =============
__launch_bounds__(256)
__global__ void pull_bf16_kernel(const int* __restrict__ rowptr, const int* __restrict__ csr_src,
                                 const float* __restrict__ alpha, const uint32_t* __restrict__ Hm,
                                 const float* __restrict__ bias, float* __restrict__ Out) {
  int d = (blockIdx.x * 256 + threadIdx.x) >> 6;
  if (d >= NN) return;
  const int lane = threadIdx.x & 63;
  const int h = lane >> 3;                 // channels (2*lane, 2*lane+1) -> head lane/8
  int rs = rowptr[d], re = rowptr[d + 1];
  float acc0 = 0.f, acc1 = 0.f;
  int j = rs;
  for (; j + 4 <= re; j += 4) {
    int s0 = csr_src[j], s1 = csr_src[j + 1], s2 = csr_src[j + 2], s3 = csr_src[j + 3];
    float al0 = alpha[(size_t)j * 8 + h];
    float al1 = alpha[(size_t)(j + 1) * 8 + h];
    float al2 = alpha[(size_t)(j + 2) * 8 + h];
    float al3 = alpha[(size_t)(j + 3) * 8 + h];
    uint32_t u0 = Hm[(size_t)s0 * 64 + lane];
    uint32_t u1 = Hm[(size_t)s1 * 64 + lane];
    uint32_t u2 = Hm[(size_t)s2 * 64 + lane];
    uint32_t u3 = Hm[(size_t)s3 * 64 + lane];
    acc0 = fmaf(al0, bflo(u0), acc0); acc1 = fmaf(al0, bfhi(u0), acc1);
    acc0 = fmaf(al1, bflo(u1), acc0); acc1 = fmaf(al1, bfhi(u1), acc1);
    acc0 = fmaf(al2, bflo(u2), acc0); acc1 = fmaf(al2, bfhi(u2), acc1);
    acc0 = fmaf(al3, bflo(u3), acc0); acc1 = fmaf(al3, bfhi(u3), acc1);
  }
  for (; j < re; ++j) {
    int s0 = csr_src[j];
    float al = alpha[(size_t)j * 8 + h];
    uint32_t u = Hm[(size_t)s0 * 64 + lane];
    acc0 = fmaf(al, bflo(u), acc0);
    acc1 = fmaf(al, bfhi(u), acc1);
  }
  float2 b = *(const float2*)&bias[lane * 2];
  float v0 = acc0 + b.x, v1 = acc1 + b.y;
  v0 = v0 > 0.f ? v0 : expm1f(v0);
  v1 = v1 > 0.f ? v1 : expm1f(v1);
  float2 o; o.x = v0; o.y = v1;
  *(float2*)&Out[(size_t)d * 128 + lane * 2] = o;
}

// ================= pull f32 (g4, F=2) =================
template<int H, int C>
__launch_bounds__(256)
__global__ void pull_kernel(const int* __restrict__ rowptr, const int* __restrict__ csr_src,
                            const float* __restrict__ alpha, const float* __restrict__ Hm,
                            const float* __restrict__ bias, float* __restrict__ Out) {
  constexpr int F = H * C;
  constexpr int NPB = 256 / F;
  int d = blockIdx.x * NPB + threadIdx.x / F;
  if (d >= NN) return;
  int f = threadIdx.x & (F - 1);
  int h = f / C;
  int rs = rowptr[d], re = rowptr[d + 1];
  float acc = 0.f;
  int j = rs;
  for (; j + 4 <= re; j += 4) {
    int s0 = csr_src[j], s1 = csr_src[j + 1], s2 = csr_src[j + 2], s3 = csr_src[j + 3];
    float a0 = alpha[(size_t)j * H + h], a1 = alpha[(size_t)(j + 1) * H + h];
    float a2 = alpha[(size_t)(j + 2) * H + h], a3 = alpha[(size_t)(j + 3) * H + h];
    float h0 = Hm[(size_t)s0 * F + f], h1 = Hm[(size_t)s1 * F + f];
    float h2 = Hm[(size_t)s2 * F + f], h3 = Hm[(size_t)s3 * F + f];
    acc = fmaf(a0, h0, acc); acc = fmaf(a1, h1, acc);
    acc = fmaf(a2, h2, acc); acc = fmaf(a3, h3, acc);
  }
  for (; j < re; ++j)
    acc = fmaf(alpha[(size_t)j * H + h], Hm[(size_t)csr_src[j] * F + f], acc);
  float v = acc + bias[f];
  Out[(size_t)d * F + f] = v > 0.f ? v : expm1f(v);
}

// ================= pull-based GCN (f32, 4-edge unroll) =================
__launch_bounds__(256)
__global__ void gcn_pull_kernel(const int* __restrict__ rowptr, const int* __restrict__ csr_src,
                                const float* __restrict__ dinv, const float* __restrict__ Hm,
                                const float* __restrict__ bias, float* __restrict__ Out) {
  int d = blockIdx.x * 16 + threadIdx.x / 16;
  if (d >= NN) return;
  int f = threadIdx.x & 15;
  int rs = rowptr[d], re = rowptr[d + 1];
  float acc = 0.f;
  int j = rs;
  for (; j + 4 <= re; j += 4) {
    int s0 = csr_src[j], s1 = csr_src[j + 1], s2 = csr_src[j + 2], s3 = csr_src[j + 3];
    float d0 = dinv[s0], d1 = dinv[s1], d2 = dinv[s2], d3 = dinv[s3];
    float h0 = Hm[(size_t)s0 * 16 + f], h1 = Hm[(size_t)s1 * 16 + f];
    float h2 = Hm[(size_t)s2 * 16 + f], h3 = Hm[(size_t)s3 * 16 + f];
    acc = fmaf(d0, h0, acc); acc = fmaf(d1, h1, acc);
    acc = fmaf(d2, h2, acc); acc = fmaf(d3, h3, acc);
  }
  for (; j < re; ++j) {
    int sn = csr_src[j];
    acc = fmaf(dinv[sn], Hm[(size_t)sn * 16 + f], acc);
  }
  float v = acc * dinv[d] + bias[f];
  Out[(size_t)d * 16 + f] = v > 0.f ? v : expm1f(v);
}

// ---------------- final concat + log_softmax ----------------
__launch_bounds__(256)
__global__ void final_kernel(const float* __restrict__ A, float* __restrict__ Out) {
  int i = blockIdx.x * 256 + threadIdx.x;
  if (i >= HALFN) return;
  float v0 = A[(size_t)i * 2 + 0];
  float v1 = A[(size_t)i * 2 + 1];
  float v2 = A[(size_t)(i + HALFN) * 2 + 0];
  float v3 = A[(size_t)(i + HALFN) * 2 + 1];
  float m = fmaxf(fmaxf(v0, v1), fmaxf(v2, v3));
  float e0 = __expf(v0 - m), e1 = __expf(v1 - m), e2 = __expf(v2 - m), e3 = __expf(v3 - m);
  float l = logf(e0 + e1 + e2 + e3) + m;
  Out[(size_t)i * 4 + 0] = v0 - l;
  Out[(size_t)i * 4 + 1] = v1 - l;
  Out[(size_t)i * 4 + 2] = v2 - l;
  Out[(size_t)i * 4 + 3] = v3 - l;
}

// ---------------- one bf16 GAT layer (H=8, C=16) ----------------
template<int K>
static void run_gat128(const float* Xin, const float* W, const float* aS, const float* aD,
                       const float* bias, const int* rowptr, const int* csr_src,
                       uint16_t* hbf, float* bufOut, float* S, float* T, float* alpha,
                       hipStream_t stream) {
  gemm_bf16_kernel<K><<<(NN + 63) / 64, 256, 0, stream>>>(Xin, W, hbf, NN);
  score_bf16_kernel<8, 16><<<(NN * 8 + 255) / 256, 256, 0, stream>>>(
      (const uint32_t*)hbf, aS, aD, S, T, NN);
  attn_kernel<8><<<(NN * 64 + 255) / 256, 256, 0, stream>>>(rowptr, csr_src, S, T, alpha);
  pull_bf16_kernel<<<(NN * 64 + 255) / 256, 256, 0, stream>>>(
      rowptr, csr_src, alpha, (const uint32_t*)hbf, bias, bufOut);
}

extern "C" void kernel_launch(void* const* d_in, const int* in_sizes, int n_in,
                              void* d_out, int out_size, void* d_ws, size_t ws_size,
                              hipStream_t stream) {
  const float* x     = (const float*)d_in[0];
  const int*   eidx  = (const int*)d_in[1];
  const int*   esrc  = eidx;
  const int*   edst  = eidx + NE;
  const float* gcn_w = (const float*)d_in[2];
  const float* gcn_b = (const float*)d_in[3];

  char* ws = (char*)d_ws;
  float*    bufA   = (float*)   (ws + 0);            // N*128 f32 (layer out)
  uint16_t* hbf    = (uint16_t*)(ws + 51200000);     // N*128 bf16 (post-GEMM h)
  float*    bufB   = (float*)   (ws + 76800000);     // N*16 f32 (GCN h / g4 h)
  float*    Sb     = (float*)   (ws + 83200000);     // N*8
  float*    Tb     = (float*)   (ws + 86400000);     // N*8
  float*    alpha  = (float*)   (ws + 89600000);     // ET*8 f32 (CSR order)
  int*      rowptr = (int*)     (ws + 144000000);    // NN+1
  int*      cursor = (int*)     (ws + 144400128);    // NN (also degi)
  int*      csr    = (int*)     (ws + 144800256);    // ET
  float*    dinv   = (float*)   (ws + 151600256);    // NN
  int*      bsums  = (int*)     (ws + 152000256);    // ~98

  constexpr int NB_SCAN = (NN + SCB - 1) / SCB;  // 98

  // ---------------- CSR build ----------------
  hipMemsetAsync(cursor, 0, (size_t)NN * 4, stream);
  deg_int_kernel<<<(ET + 255) / 256, 256, 0, stream>>>(edst, cursor);
  scan1_kernel<<<NB_SCAN, 256, 0, stream>>>(cursor, rowptr, bsums);
  scan2_kernel<<<1, 256, 0, stream>>>(bsums, NB_SCAN);
  scan3_kernel<<<(NN + 256) / 256, 256, 0, stream>>>(rowptr, bsums);
  dinv_kernel<<<(NN + 255) / 256, 256, 0, stream>>>(rowptr, dinv);
  hipMemsetAsync(cursor, 0, (size_t)NN * 4, stream);
  fill_kernel<<<(ET + 255) / 256, 256, 0, stream>>>(esrc, edst, rowptr, cursor, csr);

  // ---------------- GCN layer: x[n,128] -> bufA[n,16] ----------------
  {
    constexpr int RT = (256 / (16 / 4)) * 2;  // 128 rows/tile
    int tiles = (NN + RT - 1) / RT;
    if (tiles > 4096) tiles = 4096;
    gemm4_kernel<128, 16><<<tiles, 256, 0, stream>>>(x, gcn_w, bufB, NN);
  }
  gcn_pull_kernel<<<(NN + 15) / 16, 256, 0, stream>>>(rowptr, csr, dinv, bufB, gcn_b, bufA);

  // ---------------- GAT layers 1-3 (bf16 h) ----------------
  run_gat128<16>(bufA, (const float*)d_in[4], (const float*)d_in[5], (const float*)d_in[6],
                 (const float*)d_in[7], rowptr, csr, hbf, bufA, Sb, Tb, alpha, stream);
  run_gat128<128>(bufA, (const float*)d_in[8], (const float*)d_in[9], (const float*)d_in[10],
                  (const float*)d_in[11], rowptr, csr, hbf, bufA, Sb, Tb, alpha, stream);
  run_gat128<128>(bufA, (const float*)d_in[12], (const float*)d_in[13], (const float*)d_in[14],
                  (const float*)d_in[15], rowptr, csr, hbf, bufA, Sb, Tb, alpha, stream);

  // ---------------- GAT layer 4 (H=1, C=2, f32) ----------------
  {
    int tiles = (NN + 127) / 128;
    if (tiles > 2048) tiles = 2048;
    gemm_s_kernel<128, 2, 128><<<tiles, 256, 0, stream>>>(bufA, (const float*)d_in[16], bufB, NN);
    score_kernel<1, 2><<<(NN + 255) / 256, 256, 0, stream>>>(
        bufB, (const float*)d_in[17], (const float*)d_in[18], Sb, Tb, NN);
    attn_kernel<1><<<(NN * 64 + 255) / 256, 256, 0, stream>>>(rowptr, csr, Sb, Tb, alpha);
    pull_kernel<1, 2><<<(NN + 127) / 128, 256, 0, stream>>>(rowptr, csr, alpha, bufB,
                                                            (const float*)d_in[19], bufA);
  }

  // ---------------- concat + log_softmax -> d_out [HALFN,4] ----------------
  final_kernel<<<(HALFN + 255) / 256, 256, 0, stream>>>(bufA, (float*)d_out);
}

// Round 4
// 709.841 us; speedup vs baseline: 4.9007x; 1.1401x over previous
//
#include <hip/hip_runtime.h>
#include <cstddef>
#include <cstdint>

#define NN 100000
#define NE 1600000
#define ET (NE + NN)
#define HALFN (NN / 2)
#define NEG_SLOPE 0.2f
#define SCB 1024   // elements per scan block
#define DMAX 96    // per-node LDS alpha capacity in fused kernel (max degree ~45)
#define RP 8       // scatter regions (one per XCD)
#define RNODES (NN / RP)
#define CHUNK 8192

__device__ __forceinline__ float lrelu(float x) { return x > 0.f ? x : NEG_SLOPE * x; }

// ---- bf16 helpers (RNE pack, cheap unpack of a u32 holding 2 bf16) ----
__device__ __forceinline__ uint16_t f2bf(float f) {
  uint32_t u = __float_as_uint(f);
  uint32_t r = u + 0x7fffu + ((u >> 16) & 1u);
  return (uint16_t)(r >> 16);
}
__device__ __forceinline__ float bflo(uint32_t u) { return __uint_as_float(u << 16); }
__device__ __forceinline__ float bfhi(uint32_t u) { return __uint_as_float(u & 0xffff0000u); }

// ---------------- GEMM (f32 out), M % 4 == 0 ----------------
template<int K, int M>
__launch_bounds__(256)
__global__ void gemm4_kernel(const float* __restrict__ X, const float* __restrict__ W,
                             float* __restrict__ Y, int n) {
  constexpr int CG = M / 4;
  constexpr int RG = 256 / CG;
  constexpr int RPT = 2;
  constexpr int RT = RG * RPT;
  constexpr int KP = K + 1;
  __shared__ __align__(16) float sW[K * M];
  __shared__ float sX[RT * KP];
  for (int i = threadIdx.x; i < K * M; i += 256) sW[i] = W[i];
  const int jg = threadIdx.x % CG;
  const int rg = threadIdx.x / CG;
  const int r0 = rg * RPT;
  for (int base = blockIdx.x * RT; base < n; base += gridDim.x * RT) {
    __syncthreads();
    const int nrows = (n - base) < RT ? (n - base) : RT;
    for (int i = threadIdx.x; i < nrows * K; i += 256) {
      int r = i / K, c = i - r * K;
      sX[r * KP + c] = X[(size_t)base * K + i];
    }
    __syncthreads();
    float acc[RPT][4];
    #pragma unroll
    for (int rr = 0; rr < RPT; ++rr) acc[rr][0] = acc[rr][1] = acc[rr][2] = acc[rr][3] = 0.f;
    #pragma unroll 4
    for (int k = 0; k < K; ++k) {
      const float4 w = *(const float4*)&sW[k * M + jg * 4];
      #pragma unroll
      for (int rr = 0; rr < RPT; ++rr) {
        const float xv = sX[(r0 + rr) * KP + k];
        acc[rr][0] = fmaf(xv, w.x, acc[rr][0]);
        acc[rr][1] = fmaf(xv, w.y, acc[rr][1]);
        acc[rr][2] = fmaf(xv, w.z, acc[rr][2]);
        acc[rr][3] = fmaf(xv, w.w, acc[rr][3]);
      }
    }
    #pragma unroll
    for (int rr = 0; rr < RPT; ++rr) {
      if (r0 + rr < nrows) {
        float4 o = make_float4(acc[rr][0], acc[rr][1], acc[rr][2], acc[rr][3]);
        *(float4*)&Y[(size_t)(base + r0 + rr) * M + jg * 4] = o;
      }
    }
  }
}

// ---------------- GEMM M=128, bf16 output, two 64-col halves ----------------
template<int K>
__launch_bounds__(256)
__global__ void gemm_bf16_kernel(const float* __restrict__ X, const float* __restrict__ W,
                                 uint16_t* __restrict__ Y, int n) {
  constexpr int M = 128;
  constexpr int KP = K + 4;
  __shared__ __align__(16) float sW[K * 64];
  __shared__ __align__(16) float sX[64 * KP];
  const int jg = threadIdx.x & 15;
  const int rg = threadIdx.x >> 4;
  for (int base = blockIdx.x * 64; base < n; base += gridDim.x * 64) {
    __syncthreads();
    const int nrows = (n - base) < 64 ? (n - base) : 64;
    for (int i = threadIdx.x; i < nrows * (K / 4); i += 256) {
      int r = i / (K / 4), c = i - r * (K / 4);
      float4 v = *(const float4*)&X[(size_t)(base + r) * K + c * 4];
      *(float4*)&sX[r * KP + c * 4] = v;
    }
    #pragma unroll
    for (int mh = 0; mh < 2; ++mh) {
      __syncthreads();
      for (int i = threadIdx.x; i < K * 16; i += 256) {
        int k = i >> 4, c = i & 15;
        float4 v = *(const float4*)&W[(size_t)k * M + mh * 64 + c * 4];
        *(float4*)&sW[k * 64 + c * 4] = v;
      }
      __syncthreads();
      float acc[4][4];
      #pragma unroll
      for (int rr = 0; rr < 4; ++rr)
        acc[rr][0] = acc[rr][1] = acc[rr][2] = acc[rr][3] = 0.f;
      for (int k0 = 0; k0 < K; k0 += 4) {
        float xr[4][4];
        #pragma unroll
        for (int rr = 0; rr < 4; ++rr) {
          float4 v = *(const float4*)&sX[(rg * 4 + rr) * KP + k0];
          xr[rr][0] = v.x; xr[rr][1] = v.y; xr[rr][2] = v.z; xr[rr][3] = v.w;
        }
        #pragma unroll
        for (int kk = 0; kk < 4; ++kk) {
          const float4 w = *(const float4*)&sW[(k0 + kk) * 64 + jg * 4];
          #pragma unroll
          for (int rr = 0; rr < 4; ++rr) {
            acc[rr][0] = fmaf(xr[rr][kk], w.x, acc[rr][0]);
            acc[rr][1] = fmaf(xr[rr][kk], w.y, acc[rr][1]);
            acc[rr][2] = fmaf(xr[rr][kk], w.z, acc[rr][2]);
            acc[rr][3] = fmaf(xr[rr][kk], w.w, acc[rr][3]);
          }
        }
      }
      #pragma unroll
      for (int rr = 0; rr < 4; ++rr) {
        int r = rg * 4 + rr;
        if (r < nrows) {
          ushort4 p;
          p.x = f2bf(acc[rr][0]); p.y = f2bf(acc[rr][1]);
          p.z = f2bf(acc[rr][2]); p.w = f2bf(acc[rr][3]);
          *(ushort4*)&Y[(size_t)(base + r) * M + mh * 64 + jg * 4] = p;
        }
      }
    }
  }
}

// ---------------- GEMM, small M (M=2), f32 ----------------
template<int K, int M, int ROWS>
__launch_bounds__(256)
__global__ void gemm_s_kernel(const float* __restrict__ X, const float* __restrict__ W,
                              float* __restrict__ Y, int n) {
  constexpr int KP = K + 1;
  __shared__ float sW[K * M];
  __shared__ float sX[ROWS * KP];
  for (int i = threadIdx.x; i < K * M; i += 256) sW[i] = W[i];
  for (int base = blockIdx.x * ROWS; base < n; base += gridDim.x * ROWS) {
    __syncthreads();
    const int nrows = (n - base) < ROWS ? (n - base) : ROWS;
    for (int i = threadIdx.x; i < nrows * K; i += 256) {
      int r = i / K, c = i - r * K;
      sX[r * KP + c] = X[(size_t)base * K + i];
    }
    __syncthreads();
    for (int o = threadIdx.x; o < nrows * M; o += 256) {
      int r = o / M, j = o - r * M;
      float a = 0.f;
      #pragma unroll
      for (int k = 0; k < K; ++k) a = fmaf(sX[r * KP + k], sW[k * M + j], a);
      Y[(size_t)(base + r) * M + j] = a;
    }
  }
}

// ---------------- scores from bf16 h ----------------
template<int H, int C>
__launch_bounds__(256)
__global__ void score_bf16_kernel(const uint32_t* __restrict__ Hm,
                                  const float* __restrict__ aS, const float* __restrict__ aD,
                                  float* __restrict__ S, float* __restrict__ T, int n) {
  int idx = blockIdx.x * 256 + threadIdx.x;
  if (idx >= n * H) return;
  int h = idx & (H - 1);
  const uint32_t* hp = Hm + (size_t)idx * (C / 2);
  float s = 0.f, t = 0.f;
  #pragma unroll
  for (int c2 = 0; c2 < C / 2; ++c2) {
    uint32_t u = hp[c2];
    float v0 = bflo(u), v1 = bfhi(u);
    s = fmaf(v0, aS[h * C + 2 * c2], s);
    s = fmaf(v1, aS[h * C + 2 * c2 + 1], s);
    t = fmaf(v0, aD[h * C + 2 * c2], t);
    t = fmaf(v1, aD[h * C + 2 * c2 + 1], t);
  }
  S[idx] = s;
  T[idx] = t;
}

// ---------------- scores from f32 h (g4) ----------------
template<int H, int C>
__launch_bounds__(256)
__global__ void score_kernel(const float* __restrict__ Hm,
                             const float* __restrict__ aS, const float* __restrict__ aD,
                             float* __restrict__ S, float* __restrict__ T, int n) {
  int idx = blockIdx.x * 256 + threadIdx.x;
  if (idx >= n * H) return;
  int h = idx & (H - 1);
  const float* hp = Hm + (size_t)idx * C;
  float s = 0.f, t = 0.f;
  #pragma unroll
  for (int c = 0; c < C; ++c) {
    float v = hp[c];
    s = fmaf(v, aS[h * C + c], s);
    t = fmaf(v, aD[h * C + c], t);
  }
  S[idx] = s;
  T[idx] = t;
}

// ================= CSR build =================
// single atomic pass: per-edge arrival rank + (implicitly) degrees in cursor
__launch_bounds__(256)
__global__ void rank_kernel(const int* __restrict__ edst, int* __restrict__ cursor,
                            int* __restrict__ rank) {
  int e = blockIdx.x * 256 + threadIdx.x;
  if (e >= ET) return;
  int dn = e < NE ? edst[e] : e - NE;
  rank[e] = atomicAdd(&cursor[dn], 1);
}

__launch_bounds__(256)
__global__ void scan1_kernel(const int* __restrict__ degi, int* __restrict__ rowptr,
                             int* __restrict__ bsums) {
  __shared__ int sd[256];
  int t = threadIdx.x;
  int base = blockIdx.x * SCB + t * 4;
  int v0 = base + 0 < NN ? degi[base + 0] : 0;
  int v1 = base + 1 < NN ? degi[base + 1] : 0;
  int v2 = base + 2 < NN ? degi[base + 2] : 0;
  int v3 = base + 3 < NN ? degi[base + 3] : 0;
  int s = v0 + v1 + v2 + v3;
  sd[t] = s;
  __syncthreads();
  for (int off = 1; off < 256; off <<= 1) {
    int x = (t >= off) ? sd[t - off] : 0;
    __syncthreads();
    sd[t] += x;
    __syncthreads();
  }
  int excl = sd[t] - s;
  if (t == 255) bsums[blockIdx.x] = sd[255];
  if (base + 0 < NN) rowptr[base + 0] = excl;
  excl += v0;
  if (base + 1 < NN) rowptr[base + 1] = excl;
  excl += v1;
  if (base + 2 < NN) rowptr[base + 2] = excl;
  excl += v2;
  if (base + 3 < NN) rowptr[base + 3] = excl;
}

__launch_bounds__(256)
__global__ void scan2_kernel(int* __restrict__ bsums, int nb) {
  __shared__ int sd[256];
  int t = threadIdx.x;
  int v = t < nb ? bsums[t] : 0;
  sd[t] = v;
  __syncthreads();
  for (int off = 1; off < 256; off <<= 1) {
    int x = (t >= off) ? sd[t - off] : 0;
    __syncthreads();
    sd[t] += x;
    __syncthreads();
  }
  if (t < nb) bsums[t] = sd[t] - v;  // exclusive
}

__launch_bounds__(256)
__global__ void scan3_kernel(int* __restrict__ rowptr, const int* __restrict__ bsums) {
  int i = blockIdx.x * 256 + threadIdx.x;
  if (i < NN) rowptr[i] += bsums[i / SCB];
  if (i == 0) rowptr[NN] = ET;
}

__launch_bounds__(256)
__global__ void dinv_kernel(const int* __restrict__ rowptr, float* __restrict__ dinv) {
  int i = blockIdx.x * 256 + threadIdx.x;
  if (i >= NN) return;
  int d = rowptr[i + 1] - rowptr[i];
  dinv[i] = d > 0 ? rsqrtf((float)d) : 0.f;
}

// atomic-free scatter, region-partitioned so each csr region is written by one XCD
__launch_bounds__(256)
__global__ void scatter_part_kernel(const int* __restrict__ esrc, const int* __restrict__ edst,
                                    const int* __restrict__ rowptr, const int* __restrict__ rank,
                                    int* __restrict__ csr_src) {
  int p = blockIdx.x & (RP - 1);      // region (maps to XCD via round-robin dispatch)
  int c = blockIdx.x >> 3;            // edge chunk
  int lo = p * RNODES, hi = lo + RNODES;
  int e0 = c * CHUNK;
  int e1 = e0 + CHUNK < ET ? e0 + CHUNK : ET;
  for (int e = e0 + threadIdx.x; e < e1; e += 256) {
    int dn = e < NE ? edst[e] : e - NE;
    if (dn >= lo && dn < hi) {
      int sn = e < NE ? esrc[e] : e - NE;
      csr_src[rowptr[dn] + rank[e]] = sn;
    }
  }
}

// ================= fused attn+pull (H=8, C=16): alpha staged in LDS ============
// one wave per dst node. Phase 1: lane=(g,h) softmax; Phase 2: lane=channel-pair.
__launch_bounds__(256)
__global__ void fused_gat_kernel(const int* __restrict__ rowptr, const int* __restrict__ csr,
                                 const float* __restrict__ S, const float* __restrict__ T,
                                 const uint32_t* __restrict__ Hm, const float* __restrict__ bias,
                                 float* __restrict__ galpha, float* __restrict__ Out) {
  __shared__ float lds_e[4][DMAX * 9];   // stride 9 -> worst 2-way bank alias (free)
  int wv = threadIdx.x >> 6;
  int lane = threadIdx.x & 63;
  int d = (blockIdx.x * 256 + threadIdx.x) >> 6;
  if (d >= NN) return;
  int rs = rowptr[d], re = rowptr[d + 1];
  int deg = re - rs;
  // ---- phase 1: softmax over edges ----
  int h = lane & 7, g = lane >> 3;
  float Th = T[(size_t)d * 8 + h];
  float m = -1e30f;
  for (int l = g; l < deg; l += 8) {
    int sn = csr[rs + l];
    float e = lrelu(S[(size_t)sn * 8 + h] + Th);
    if (l < DMAX) lds_e[wv][l * 9 + h] = e;
    else galpha[(size_t)(rs + l) * 8 + h] = e;
    m = fmaxf(m, e);
  }
  #pragma unroll
  for (int mask = 8; mask < 64; mask <<= 1) m = fmaxf(m, __shfl_xor(m, mask));
  float sum = 0.f;
  for (int l = g; l < deg; l += 8) {
    float e = (l < DMAX) ? lds_e[wv][l * 9 + h] : galpha[(size_t)(rs + l) * 8 + h];
    sum += __expf(e - m);
  }
  #pragma unroll
  for (int mask = 8; mask < 64; mask <<= 1) sum += __shfl_xor(sum, mask);
  float inv = 1.f / (sum + 1e-16f);
  for (int l = g; l < deg; l += 8) {
    if (l < DMAX) {
      float e = lds_e[wv][l * 9 + h];
      lds_e[wv][l * 9 + h] = __expf(e - m) * inv;
    } else {
      float e = galpha[(size_t)(rs + l) * 8 + h];
      galpha[(size_t)(rs + l) * 8 + h] = __expf(e - m) * inv;
    }
  }
  // ---- phase 2: weighted gather of h rows (per-wave, no barrier needed) ----
  int hp = lane >> 3;                    // head for channels (2*lane, 2*lane+1)
  float acc0 = 0.f, acc1 = 0.f;
  int dmin = deg < DMAX ? deg : DMAX;
  int l = 0;
  for (; l + 4 <= dmin; l += 4) {
    int s0 = csr[rs + l], s1 = csr[rs + l + 1], s2 = csr[rs + l + 2], s3 = csr[rs + l + 3];
    float a0 = lds_e[wv][(l + 0) * 9 + hp];
    float a1 = lds_e[wv][(l + 1) * 9 + hp];
    float a2 = lds_e[wv][(l + 2) * 9 + hp];
    float a3 = lds_e[wv][(l + 3) * 9 + hp];
    uint32_t u0 = Hm[(size_t)s0 * 64 + lane];
    uint32_t u1 = Hm[(size_t)s1 * 64 + lane];
    uint32_t u2 = Hm[(size_t)s2 * 64 + lane];
    uint32_t u3 = Hm[(size_t)s3 * 64 + lane];
    acc0 = fmaf(a0, bflo(u0), acc0); acc1 = fmaf(a0, bfhi(u0), acc1);
    acc0 = fmaf(a1, bflo(u1), acc0); acc1 = fmaf(a1, bfhi(u1), acc1);
    acc0 = fmaf(a2, bflo(u2), acc0); acc1 = fmaf(a2, bfhi(u2), acc1);
    acc0 = fmaf(a3, bflo(u3), acc0); acc1 = fmaf(a3, bfhi(u3), acc1);
  }
  for (; l < dmin; ++l) {
    int sn = csr[rs + l];
    float a = lds_e[wv][l * 9 + hp];
    uint32_t u = Hm[(size_t)sn * 64 + lane];
    acc0 = fmaf(a, bflo(u), acc0);
    acc1 = fmaf(a, bfhi(u), acc1);
  }
  for (; l < deg; ++l) {                  // rare spill path
    int sn = csr[rs + l];
    float a = galpha[(size_t)(rs + l) * 8 + hp];
    uint32_t u = Hm[(size_t)sn * 64 + lane];
    acc0 = fmaf(a, bflo(u), acc0);
    acc1 = fmaf(a, bfhi(u), acc1);
  }
  float2 b = *(const float2*)&bias[lane * 2];
  float v0 = acc0 + b.x, v1 = acc1 + b.y;
  v0 = v0 > 0.f ? v0 : expm1f(v0);
  v1 = v1 > 0.f ? v1 : expm1f(v1);
  float2 o; o.x = v0; o.y = v1;
  *(float2*)&Out[(size_t)d * 128 + lane * 2] = o;
}

// ================= attention (H=1, g4) =================
template<int H>
__launch_bounds__(256)
__global__ void attn_kernel(const int* __restrict__ rowptr, const int* __restrict__ csr_src,
                            const float* __restrict__ S, const float* __restrict__ T,
                            float* __restrict__ alpha) {
  constexpr int NG = 64 / H;
  int wid = (blockIdx.x * 256 + threadIdx.x) >> 6;
  if (wid >= NN) return;
  int lane = threadIdx.x & 63;
  int h = lane & (H - 1);
  int g = lane / H;
  int rs = rowptr[wid], re = rowptr[wid + 1];
  float Th = T[(size_t)wid * H + h];
  int j0 = rs + g;
  float e0 = -1e30f, e1 = -1e30f, e2 = -1e30f, e3 = -1e30f;
  if (j0 < re)          e0 = lrelu(S[(size_t)csr_src[j0] * H + h] + Th);
  if (j0 + NG < re)     e1 = lrelu(S[(size_t)csr_src[j0 + NG] * H + h] + Th);
  if (j0 + 2 * NG < re) e2 = lrelu(S[(size_t)csr_src[j0 + 2 * NG] * H + h] + Th);
  if (j0 + 3 * NG < re) e3 = lrelu(S[(size_t)csr_src[j0 + 3 * NG] * H + h] + Th);
  float m = fmaxf(fmaxf(e0, e1), fmaxf(e2, e3));
  for (int j = j0 + 4 * NG; j < re; j += NG) {
    float e = lrelu(S[(size_t)csr_src[j] * H + h] + Th);
    alpha[(size_t)j * H + h] = e;
    m = fmaxf(m, e);
  }
  #pragma unroll
  for (int mask = H; mask < 64; mask <<= 1) m = fmaxf(m, __shfl_xor(m, mask));
  float sum = __expf(e0 - m) + __expf(e1 - m) + __expf(e2 - m) + __expf(e3 - m);
  for (int j = j0 + 4 * NG; j < re; j += NG)
    sum += __expf(alpha[(size_t)j * H + h] - m);
  #pragma unroll
  for (int mask = H; mask < 64; mask <<= 1) sum += __shfl_xor(sum, mask);
  float inv = 1.f / (sum + 1e-16f);
  if (j0 < re)          alpha[(size_t)j0 * H + h]            = __expf(e0 - m) * inv;
  if (j0 + NG < re)     alpha[(size_t)(j0 + NG) * H + h]     = __expf(e1 - m) * inv;
  if (j0 + 2 * NG < re) alpha[(size_t)(j0 + 2 * NG) * H + h] = __expf(e2 - m) * inv;
  if (j0 + 3 * NG < re) alpha[(size_t)(j0 + 3 * NG) * H + h] = __expf(e3 - m) * inv;
  for (int j = j0 + 4 * NG; j < re; j += NG)
    alpha[(size_t)j * H + h] = __expf(alpha[(size_t)j * H + h] - m) * inv;
}

// ================= pull f32 (g4, F=2) =================
template<int H, int C>
__launch_bounds__(256)
__global__ void pull_kernel(const int* __restrict__ rowptr, const int* __restrict__ csr_src,
                            const float* __restrict__ alpha, const float* __restrict__ Hm,
                            const float* __restrict__ bias, float* __restrict__ Out) {
  constexpr int F = H * C;
  constexpr int NPB = 256 / F;
  int d = blockIdx.x * NPB + threadIdx.x / F;
  if (d >= NN) return;
  int f = threadIdx.x & (F - 1);
  int h = f / C;
  int rs = rowptr[d], re = rowptr[d + 1];
  float acc = 0.f;
  int j = rs;
  for (; j + 4 <= re; j += 4) {
    int s0 = csr_src[j], s1 = csr_src[j + 1], s2 = csr_src[j + 2], s3 = csr_src[j + 3];
    float a0 = alpha[(size_t)j * H + h], a1 = alpha[(size_t)(j + 1) * H + h];
    float a2 = alpha[(size_t)(j + 2) * H + h], a3 = alpha[(size_t)(j + 3) * H + h];
    float h0 = Hm[(size_t)s0 * F + f], h1 = Hm[(size_t)s1 * F + f];
    float h2 = Hm[(size_t)s2 * F + f], h3 = Hm[(size_t)s3 * F + f];
    acc = fmaf(a0, h0, acc); acc = fmaf(a1, h1, acc);
    acc = fmaf(a2, h2, acc); acc = fmaf(a3, h3, acc);
  }
  for (; j < re; ++j)
    acc = fmaf(alpha[(size_t)j * H + h], Hm[(size_t)csr_src[j] * F + f], acc);
  float v = acc + bias[f];
  Out[(size_t)d * F + f] = v > 0.f ? v : expm1f(v);
}

// ================= pull-based GCN (f32, 4-edge unroll) =================
__launch_bounds__(256)
__global__ void gcn_pull_kernel(const int* __restrict__ rowptr, const int* __restrict__ csr_src,
                                const float* __restrict__ dinv, const float* __restrict__ Hm,
                                const float* __restrict__ bias, float* __restrict__ Out) {
  int d = blockIdx.x * 16 + threadIdx.x / 16;
  if (d >= NN) return;
  int f = threadIdx.x & 15;
  int rs = rowptr[d], re = rowptr[d + 1];
  float acc = 0.f;
  int j = rs;
  for (; j + 4 <= re; j += 4) {
    int s0 = csr_src[j], s1 = csr_src[j + 1], s2 = csr_src[j + 2], s3 = csr_src[j + 3];
    float d0 = dinv[s0], d1 = dinv[s1], d2 = dinv[s2], d3 = dinv[s3];
    float h0 = Hm[(size_t)s0 * 16 + f], h1 = Hm[(size_t)s1 * 16 + f];
    float h2 = Hm[(size_t)s2 * 16 + f], h3 = Hm[(size_t)s3 * 16 + f];
    acc = fmaf(d0, h0, acc); acc = fmaf(d1, h1, acc);
    acc = fmaf(d2, h2, acc); acc = fmaf(d3, h3, acc);
  }
  for (; j < re; ++j) {
    int sn = csr_src[j];
    acc = fmaf(dinv[sn], Hm[(size_t)sn * 16 + f], acc);
  }
  float v = acc * dinv[d] + bias[f];
  Out[(size_t)d * 16 + f] = v > 0.f ? v : expm1f(v);
}

// ---------------- final concat + log_softmax ----------------
__launch_bounds__(256)
__global__ void final_kernel(const float* __restrict__ A, float* __restrict__ Out) {
  int i = blockIdx.x * 256 + threadIdx.x;
  if (i >= HALFN) return;
  float v0 = A[(size_t)i * 2 + 0];
  float v1 = A[(size_t)i * 2 + 1];
  float v2 = A[(size_t)(i + HALFN) * 2 + 0];
  float v3 = A[(size_t)(i + HALFN) * 2 + 1];
  float m = fmaxf(fmaxf(v0, v1), fmaxf(v2, v3));
  float e0 = __expf(v0 - m), e1 = __expf(v1 - m), e2 = __expf(v2 - m), e3 = __expf(v3 - m);
  float l = logf(e0 + e1 + e2 + e3) + m;
  Out[(size_t)i * 4 + 0] = v0 - l;
  Out[(size_t)i * 4 + 1] = v1 - l;
  Out[(size_t)i * 4 + 2] = v2 - l;
  Out[(size_t)i * 4 + 3] = v3 - l;
}

// ---------------- one bf16 GAT layer (H=8, C=16) ----------------
template<int K>
static void run_gat128(const float* Xin, const float* W, const float* aS, const float* aD,
                       const float* bias, const int* rowptr, const int* csr,
                       uint16_t* hbf, float* bufOut, float* S, float* T, float* galpha,
                       hipStream_t stream) {
  gemm_bf16_kernel<K><<<(NN + 63) / 64, 256, 0, stream>>>(Xin, W, hbf, NN);
  score_bf16_kernel<8, 16><<<(NN * 8 + 255) / 256, 256, 0, stream>>>(
      (const uint32_t*)hbf, aS, aD, S, T, NN);
  fused_gat_kernel<<<(NN * 64 + 255) / 256, 256, 0, stream>>>(
      rowptr, csr, S, T, (const uint32_t*)hbf, bias, galpha, bufOut);
}

extern "C" void kernel_launch(void* const* d_in, const int* in_sizes, int n_in,
                              void* d_out, int out_size, void* d_ws, size_t ws_size,
                              hipStream_t stream) {
  const float* x     = (const float*)d_in[0];
  const int*   eidx  = (const int*)d_in[1];
  const int*   esrc  = eidx;
  const int*   edst  = eidx + NE;
  const float* gcn_w = (const float*)d_in[2];
  const float* gcn_b = (const float*)d_in[3];

  char* ws = (char*)d_ws;
  float*    bufA   = (float*)   (ws + 0);            // N*128 f32 (layer out)
  uint16_t* hbf    = (uint16_t*)(ws + 51200000);     // N*128 bf16 (post-GEMM h)
  float*    bufB   = (float*)   (ws + 76800000);     // N*16 f32 (GCN h / g4 h)
  float*    Sb     = (float*)   (ws + 83200000);     // N*8
  float*    Tb     = (float*)   (ws + 86400000);     // N*8
  float*    alpha  = (float*)   (ws + 89600000);     // ET*8 f32 (g4 + spill)
  int*      rowptr = (int*)     (ws + 144000000);    // NN+1
  int*      cursor = (int*)     (ws + 144400128);    // NN (degrees)
  int*      csr    = (int*)     (ws + 144800256);    // ET
  float*    dinv   = (float*)   (ws + 151600256);    // NN
  int*      bsums  = (int*)     (ws + 152000256);    // ~98
  int*      rank   = (int*)     (ws + 152001536);    // ET

  constexpr int NB_SCAN = (NN + SCB - 1) / SCB;  // 98

  // ---------------- CSR build ----------------
  hipMemsetAsync(cursor, 0, (size_t)NN * 4, stream);
  rank_kernel<<<(ET + 255) / 256, 256, 0, stream>>>(edst, cursor, rank);
  scan1_kernel<<<NB_SCAN, 256, 0, stream>>>(cursor, rowptr, bsums);
  scan2_kernel<<<1, 256, 0, stream>>>(bsums, NB_SCAN);
  scan3_kernel<<<(NN + 256) / 256, 256, 0, stream>>>(rowptr, bsums);
  dinv_kernel<<<(NN + 255) / 256, 256, 0, stream>>>(rowptr, dinv);
  {
    int nch = (ET + CHUNK - 1) / CHUNK;
    scatter_part_kernel<<<nch * RP, 256, 0, stream>>>(esrc, edst, rowptr, rank, csr);
  }

  // ---------------- GCN layer: x[n,128] -> bufA[n,16] ----------------
  {
    constexpr int RT = (256 / (16 / 4)) * 2;  // 128 rows/tile
    int tiles = (NN + RT - 1) / RT;
    if (tiles > 4096) tiles = 4096;
    gemm4_kernel<128, 16><<<tiles, 256, 0, stream>>>(x, gcn_w, bufB, NN);
  }
  gcn_pull_kernel<<<(NN + 15) / 16, 256, 0, stream>>>(rowptr, csr, dinv, bufB, gcn_b, bufA);

  // ---------------- GAT layers 1-3 (bf16 h, fused attn+pull) ----------------
  run_gat128<16>(bufA, (const float*)d_in[4], (const float*)d_in[5], (const float*)d_in[6],
                 (const float*)d_in[7], rowptr, csr, hbf, bufA, Sb, Tb, alpha, stream);
  run_gat128<128>(bufA, (const float*)d_in[8], (const float*)d_in[9], (const float*)d_in[10],
                  (const float*)d_in[11], rowptr, csr, hbf, bufA, Sb, Tb, alpha, stream);
  run_gat128<128>(bufA, (const float*)d_in[12], (const float*)d_in[13], (const float*)d_in[14],
                  (const float*)d_in[15], rowptr, csr, hbf, bufA, Sb, Tb, alpha, stream);

  // ---------------- GAT layer 4 (H=1, C=2, f32) ----------------
  {
    int tiles = (NN + 127) / 128;
    if (tiles > 2048) tiles = 2048;
    gemm_s_kernel<128, 2, 128><<<tiles, 256, 0, stream>>>(bufA, (const float*)d_in[16], bufB, NN);
    score_kernel<1, 2><<<(NN + 255) / 256, 256, 0, stream>>>(
        bufB, (const float*)d_in[17], (const float*)d_in[18], Sb, Tb, NN);
    attn_kernel<1><<<(NN * 64 + 255) / 256, 256, 0, stream>>>(rowptr, csr, Sb, Tb, alpha);
    pull_kernel<1, 2><<<(NN + 127) / 128, 256, 0, stream>>>(rowptr, csr, alpha, bufB,
                                                            (const float*)d_in[19], bufA);
  }

  // ---------------- concat + log_softmax -> d_out [HALFN,4] ----------------
  final_kernel<<<(HALFN + 255) / 256, 256, 0, stream>>>(bufA, (float*)d_out);
}

// Round 5
// 643.697 us; speedup vs baseline: 5.4043x; 1.1028x over previous
//
#include <hip/hip_runtime.h>
#include <cstddef>
#include <cstdint>

#define NN 100000
#define NE 1600000
#define ET (NE + NN)
#define HALFN (NN / 2)
#define NEG_SLOPE 0.2f
#define SCB 1024   // elements per scan block
#define DMAX 96    // per-node LDS alpha capacity (max degree ~45 for this graph)
#define RP 8       // scatter regions (one per XCD)
#define RNODES (NN / RP)
#define CHUNK 8192

__device__ __forceinline__ float lrelu(float x) { return x > 0.f ? x : NEG_SLOPE * x; }

// ---- bf16 helpers ----
__device__ __forceinline__ uint16_t f2bf(float f) {
  uint32_t u = __float_as_uint(f);
  uint32_t r = u + 0x7fffu + ((u >> 16) & 1u);
  return (uint16_t)(r >> 16);
}
__device__ __forceinline__ float bflo(uint32_t u) { return __uint_as_float(u << 16); }
__device__ __forceinline__ float bfhi(uint32_t u) { return __uint_as_float(u & 0xffff0000u); }

// ---------------- GEMM (f32 in/out), M % 4 == 0 (GCN) ----------------
template<int K, int M>
__launch_bounds__(256)
__global__ void gemm4_kernel(const float* __restrict__ X, const float* __restrict__ W,
                             float* __restrict__ Y, int n) {
  constexpr int CG = M / 4;
  constexpr int RG = 256 / CG;
  constexpr int RPT = 2;
  constexpr int RT = RG * RPT;
  constexpr int KP = K + 1;
  __shared__ __align__(16) float sW[K * M];
  __shared__ float sX[RT * KP];
  for (int i = threadIdx.x; i < K * M; i += 256) sW[i] = W[i];
  const int jg = threadIdx.x % CG;
  const int rg = threadIdx.x / CG;
  const int r0 = rg * RPT;
  for (int base = blockIdx.x * RT; base < n; base += gridDim.x * RT) {
    __syncthreads();
    const int nrows = (n - base) < RT ? (n - base) : RT;
    for (int i = threadIdx.x; i < nrows * K; i += 256) {
      int r = i / K, c = i - r * K;
      sX[r * KP + c] = X[(size_t)base * K + i];
    }
    __syncthreads();
    float acc[RPT][4];
    #pragma unroll
    for (int rr = 0; rr < RPT; ++rr) acc[rr][0] = acc[rr][1] = acc[rr][2] = acc[rr][3] = 0.f;
    #pragma unroll 4
    for (int k = 0; k < K; ++k) {
      const float4 w = *(const float4*)&sW[k * M + jg * 4];
      #pragma unroll
      for (int rr = 0; rr < RPT; ++rr) {
        const float xv = sX[(r0 + rr) * KP + k];
        acc[rr][0] = fmaf(xv, w.x, acc[rr][0]);
        acc[rr][1] = fmaf(xv, w.y, acc[rr][1]);
        acc[rr][2] = fmaf(xv, w.z, acc[rr][2]);
        acc[rr][3] = fmaf(xv, w.w, acc[rr][3]);
      }
    }
    #pragma unroll
    for (int rr = 0; rr < RPT; ++rr) {
      if (r0 + rr < nrows) {
        float4 o = make_float4(acc[rr][0], acc[rr][1], acc[rr][2], acc[rr][3]);
        *(float4*)&Y[(size_t)(base + r0 + rr) * M + jg * 4] = o;
      }
    }
  }
}

// ---------------- GEMM M=128, bf16 output, optional bf16 input ----------------
template<int K, bool XBF>
__launch_bounds__(256)
__global__ void gemm_bf16_kernel(const void* __restrict__ Xv, const float* __restrict__ W,
                                 uint16_t* __restrict__ Y, int n) {
  constexpr int M = 128;
  constexpr int KP = K + 4;
  __shared__ __align__(16) float sW[K * 64];
  __shared__ __align__(16) float sX[64 * KP];
  const int jg = threadIdx.x & 15;
  const int rg = threadIdx.x >> 4;
  for (int base = blockIdx.x * 64; base < n; base += gridDim.x * 64) {
    __syncthreads();
    const int nrows = (n - base) < 64 ? (n - base) : 64;
    if constexpr (XBF) {
      const uint16_t* Xb = (const uint16_t*)Xv;
      for (int i = threadIdx.x; i < nrows * (K / 4); i += 256) {
        int r = i / (K / 4), c = i - r * (K / 4);
        uint2 u = *(const uint2*)&Xb[(size_t)(base + r) * K + c * 4];
        float4 v;
        v.x = bflo(u.x); v.y = bfhi(u.x); v.z = bflo(u.y); v.w = bfhi(u.y);
        *(float4*)&sX[r * KP + c * 4] = v;
      }
    } else {
      const float* X = (const float*)Xv;
      for (int i = threadIdx.x; i < nrows * (K / 4); i += 256) {
        int r = i / (K / 4), c = i - r * (K / 4);
        float4 v = *(const float4*)&X[(size_t)(base + r) * K + c * 4];
        *(float4*)&sX[r * KP + c * 4] = v;
      }
    }
    #pragma unroll
    for (int mh = 0; mh < 2; ++mh) {
      __syncthreads();
      for (int i = threadIdx.x; i < K * 16; i += 256) {
        int k = i >> 4, c = i & 15;
        float4 v = *(const float4*)&W[(size_t)k * M + mh * 64 + c * 4];
        *(float4*)&sW[k * 64 + c * 4] = v;
      }
      __syncthreads();
      float acc[4][4];
      #pragma unroll
      for (int rr = 0; rr < 4; ++rr)
        acc[rr][0] = acc[rr][1] = acc[rr][2] = acc[rr][3] = 0.f;
      for (int k0 = 0; k0 < K; k0 += 4) {
        float xr[4][4];
        #pragma unroll
        for (int rr = 0; rr < 4; ++rr) {
          float4 v = *(const float4*)&sX[(rg * 4 + rr) * KP + k0];
          xr[rr][0] = v.x; xr[rr][1] = v.y; xr[rr][2] = v.z; xr[rr][3] = v.w;
        }
        #pragma unroll
        for (int kk = 0; kk < 4; ++kk) {
          const float4 w = *(const float4*)&sW[(k0 + kk) * 64 + jg * 4];
          #pragma unroll
          for (int rr = 0; rr < 4; ++rr) {
            acc[rr][0] = fmaf(xr[rr][kk], w.x, acc[rr][0]);
            acc[rr][1] = fmaf(xr[rr][kk], w.y, acc[rr][1]);
            acc[rr][2] = fmaf(xr[rr][kk], w.z, acc[rr][2]);
            acc[rr][3] = fmaf(xr[rr][kk], w.w, acc[rr][3]);
          }
        }
      }
      #pragma unroll
      for (int rr = 0; rr < 4; ++rr) {
        int r = rg * 4 + rr;
        if (r < nrows) {
          ushort4 p;
          p.x = f2bf(acc[rr][0]); p.y = f2bf(acc[rr][1]);
          p.z = f2bf(acc[rr][2]); p.w = f2bf(acc[rr][3]);
          *(ushort4*)&Y[(size_t)(base + r) * M + mh * 64 + jg * 4] = p;
        }
      }
    }
  }
}

// ---------------- GEMM, small M (M=2), bf16 or f32 input ----------------
template<int K, int M, int ROWS, bool XBF>
__launch_bounds__(256)
__global__ void gemm_s_kernel(const void* __restrict__ Xv, const float* __restrict__ W,
                              float* __restrict__ Y, int n) {
  constexpr int KP = K + 1;
  __shared__ float sW[K * M];
  __shared__ float sX[ROWS * KP];
  for (int i = threadIdx.x; i < K * M; i += 256) sW[i] = W[i];
  for (int base = blockIdx.x * ROWS; base < n; base += gridDim.x * ROWS) {
    __syncthreads();
    const int nrows = (n - base) < ROWS ? (n - base) : ROWS;
    if constexpr (XBF) {
      const uint16_t* Xb = (const uint16_t*)Xv;
      for (int i = threadIdx.x; i < nrows * (K / 4); i += 256) {
        int r = i / (K / 4), c = i - r * (K / 4);
        uint2 u = *(const uint2*)&Xb[(size_t)(base + r) * K + c * 4];
        sX[r * KP + c * 4 + 0] = bflo(u.x);
        sX[r * KP + c * 4 + 1] = bfhi(u.x);
        sX[r * KP + c * 4 + 2] = bflo(u.y);
        sX[r * KP + c * 4 + 3] = bfhi(u.y);
      }
    } else {
      const float* X = (const float*)Xv;
      for (int i = threadIdx.x; i < nrows * K; i += 256) {
        int r = i / K, c = i - r * K;
        sX[r * KP + c] = X[(size_t)base * K + i];
      }
    }
    __syncthreads();
    for (int o = threadIdx.x; o < nrows * M; o += 256) {
      int r = o / M, j = o - r * M;
      float a = 0.f;
      #pragma unroll
      for (int k = 0; k < K; ++k) a = fmaf(sX[r * KP + k], sW[k * M + j], a);
      Y[(size_t)(base + r) * M + j] = a;
    }
  }
}

// ---------------- scores from bf16 h ----------------
template<int H, int C>
__launch_bounds__(256)
__global__ void score_bf16_kernel(const uint32_t* __restrict__ Hm,
                                  const float* __restrict__ aS, const float* __restrict__ aD,
                                  float* __restrict__ S, float* __restrict__ T, int n) {
  int idx = blockIdx.x * 256 + threadIdx.x;
  if (idx >= n * H) return;
  int h = idx & (H - 1);
  const uint32_t* hp = Hm + (size_t)idx * (C / 2);
  float s = 0.f, t = 0.f;
  #pragma unroll
  for (int c2 = 0; c2 < C / 2; ++c2) {
    uint32_t u = hp[c2];
    float v0 = bflo(u), v1 = bfhi(u);
    s = fmaf(v0, aS[h * C + 2 * c2], s);
    s = fmaf(v1, aS[h * C + 2 * c2 + 1], s);
    t = fmaf(v0, aD[h * C + 2 * c2], t);
    t = fmaf(v1, aD[h * C + 2 * c2 + 1], t);
  }
  S[idx] = s;
  T[idx] = t;
}

// ---------------- scores from f32 h (g4) ----------------
template<int H, int C>
__launch_bounds__(256)
__global__ void score_kernel(const float* __restrict__ Hm,
                             const float* __restrict__ aS, const float* __restrict__ aD,
                             float* __restrict__ S, float* __restrict__ T, int n) {
  int idx = blockIdx.x * 256 + threadIdx.x;
  if (idx >= n * H) return;
  int h = idx & (H - 1);
  const float* hp = Hm + (size_t)idx * C;
  float s = 0.f, t = 0.f;
  #pragma unroll
  for (int c = 0; c < C; ++c) {
    float v = hp[c];
    s = fmaf(v, aS[h * C + c], s);
    t = fmaf(v, aD[h * C + c], t);
  }
  S[idx] = s;
  T[idx] = t;
}

// ================= CSR build =================
__launch_bounds__(256)
__global__ void rank_kernel(const int* __restrict__ edst, int* __restrict__ cursor,
                            int* __restrict__ rank) {
  int e = blockIdx.x * 256 + threadIdx.x;
  if (e >= ET) return;
  int dn = e < NE ? edst[e] : e - NE;
  rank[e] = atomicAdd(&cursor[dn], 1);
}

__launch_bounds__(256)
__global__ void scan1_kernel(const int* __restrict__ degi, int* __restrict__ rowptr,
                             int* __restrict__ bsums) {
  __shared__ int sd[256];
  int t = threadIdx.x;
  int base = blockIdx.x * SCB + t * 4;
  int v0 = base + 0 < NN ? degi[base + 0] : 0;
  int v1 = base + 1 < NN ? degi[base + 1] : 0;
  int v2 = base + 2 < NN ? degi[base + 2] : 0;
  int v3 = base + 3 < NN ? degi[base + 3] : 0;
  int s = v0 + v1 + v2 + v3;
  sd[t] = s;
  __syncthreads();
  for (int off = 1; off < 256; off <<= 1) {
    int x = (t >= off) ? sd[t - off] : 0;
    __syncthreads();
    sd[t] += x;
    __syncthreads();
  }
  int excl = sd[t] - s;
  if (t == 255) bsums[blockIdx.x] = sd[255];
  if (base + 0 < NN) rowptr[base + 0] = excl;
  excl += v0;
  if (base + 1 < NN) rowptr[base + 1] = excl;
  excl += v1;
  if (base + 2 < NN) rowptr[base + 2] = excl;
  excl += v2;
  if (base + 3 < NN) rowptr[base + 3] = excl;
}

__launch_bounds__(256)
__global__ void scan2_kernel(int* __restrict__ bsums, int nb) {
  __shared__ int sd[256];
  int t = threadIdx.x;
  int v = t < nb ? bsums[t] : 0;
  sd[t] = v;
  __syncthreads();
  for (int off = 1; off < 256; off <<= 1) {
    int x = (t >= off) ? sd[t - off] : 0;
    __syncthreads();
    sd[t] += x;
    __syncthreads();
  }
  if (t < nb) bsums[t] = sd[t] - v;  // exclusive
}

__launch_bounds__(256)
__global__ void scan3_kernel(int* __restrict__ rowptr, const int* __restrict__ bsums) {
  int i = blockIdx.x * 256 + threadIdx.x;
  if (i < NN) rowptr[i] += bsums[i / SCB];
  if (i == 0) rowptr[NN] = ET;
}

__launch_bounds__(256)
__global__ void dinv_kernel(const int* __restrict__ rowptr, float* __restrict__ dinv) {
  int i = blockIdx.x * 256 + threadIdx.x;
  if (i >= NN) return;
  int d = rowptr[i + 1] - rowptr[i];
  dinv[i] = d > 0 ? rsqrtf((float)d) : 0.f;
}

__launch_bounds__(256)
__global__ void scatter_part_kernel(const int* __restrict__ esrc, const int* __restrict__ edst,
                                    const int* __restrict__ rowptr, const int* __restrict__ rank,
                                    int* __restrict__ csr_src) {
  int p = blockIdx.x & (RP - 1);
  int c = blockIdx.x >> 3;
  int lo = p * RNODES, hi = lo + RNODES;
  int e0 = c * CHUNK;
  int e1 = e0 + CHUNK < ET ? e0 + CHUNK : ET;
  for (int e = e0 + threadIdx.x; e < e1; e += 256) {
    int dn = e < NE ? edst[e] : e - NE;
    if (dn >= lo && dn < hi) {
      int sn = e < NE ? esrc[e] : e - NE;
      csr_src[rowptr[dn] + rank[e]] = sn;
    }
  }
}

// ================= fused attn+pull v2 (H=8, C=16) =================
// one wave per dst. P1a: e into LDS + max. P1b: p=exp(e-m), sum. P2: uint4
// gather, 4 edges/wave-iter, 1/sum folded into epilogue. bf16 output.
__launch_bounds__(256)
__global__ void fused_gat_kernel(const int* __restrict__ rowptr, const int* __restrict__ csr,
                                 const float* __restrict__ S, const float* __restrict__ T,
                                 const uint4* __restrict__ Hm4, const float* __restrict__ bias,
                                 float* __restrict__ galpha, uint16_t* __restrict__ Outb) {
  __shared__ float lds_p[4][DMAX * 9];   // stride 9: near-conflict-free
  __shared__ int   lds_c[4][DMAX];       // csr row cache
  const int wv = threadIdx.x >> 6;
  const int lane = threadIdx.x & 63;
  const int d = (blockIdx.x * 256 + threadIdx.x) >> 6;
  if (d >= NN) return;
  const int rs = rowptr[d];
  const int deg = rowptr[d + 1] - rs;
  // ---- P1a ----
  const int h = lane & 7, g = lane >> 3;
  const float Th = T[(size_t)d * 8 + h];
  float m = -1e30f;
  for (int l = g; l < deg; l += 8) {
    int sn = csr[rs + l];
    float e = lrelu(S[(size_t)sn * 8 + h] + Th);
    if (l < DMAX) {
      lds_p[wv][l * 9 + h] = e;
      if (h == 0) lds_c[wv][l] = sn;
    } else {
      galpha[(size_t)(rs + l) * 8 + h] = e;
    }
    m = fmaxf(m, e);
  }
  #pragma unroll
  for (int mask = 8; mask < 64; mask <<= 1) m = fmaxf(m, __shfl_xor(m, mask));
  // ---- P1b ----
  float sum = 0.f;
  for (int l = g; l < deg; l += 8) {
    if (l < DMAX) {
      float p = __expf(lds_p[wv][l * 9 + h] - m);
      lds_p[wv][l * 9 + h] = p;
      sum += p;
    } else {
      float p = __expf(galpha[(size_t)(rs + l) * 8 + h] - m);
      galpha[(size_t)(rs + l) * 8 + h] = p;
      sum += p;
    }
  }
  #pragma unroll
  for (int mask = 8; mask < 64; mask <<= 1) sum += __shfl_xor(sum, mask);
  const float inv = 1.f / (sum + 1e-16f);
  // ---- P2: lane = (edge-group eg, channel-block cl) ----
  const int eg = lane >> 4;           // 0..3
  const int cl = lane & 15;           // channels cl*8 .. cl*8+7, head cl>>1
  const int hp = cl >> 1;
  const float invp = __shfl(inv, hp); // inv for head hp (uniform across groups)
  float a0 = 0.f, a1 = 0.f, a2 = 0.f, a3 = 0.f, a4 = 0.f, a5 = 0.f, a6 = 0.f, a7 = 0.f;
  const int dmin = deg < DMAX ? deg : DMAX;
  #pragma unroll 2
  for (int l0 = 0; l0 < dmin; l0 += 4) {
    int l = l0 + eg;
    bool v = l < dmin;
    int lc = v ? l : 0;
    int sn = lds_c[wv][lc];
    float p = lds_p[wv][lc * 9 + hp];
    if (!v) p = 0.f;
    uint4 u = Hm4[(size_t)sn * 16 + cl];
    a0 = fmaf(p, bflo(u.x), a0); a1 = fmaf(p, bfhi(u.x), a1);
    a2 = fmaf(p, bflo(u.y), a2); a3 = fmaf(p, bfhi(u.y), a3);
    a4 = fmaf(p, bflo(u.z), a4); a5 = fmaf(p, bfhi(u.z), a5);
    a6 = fmaf(p, bflo(u.w), a6); a7 = fmaf(p, bfhi(u.w), a7);
  }
  for (int l0 = dmin; l0 < deg; l0 += 4) {   // spill path (not taken on this graph)
    int l = l0 + eg;
    bool v = l < deg;
    int idx = v ? (rs + l) : rs;
    float p = v ? galpha[(size_t)idx * 8 + hp] : 0.f;
    int sn = csr[idx];
    uint4 u = Hm4[(size_t)sn * 16 + cl];
    a0 = fmaf(p, bflo(u.x), a0); a1 = fmaf(p, bfhi(u.x), a1);
    a2 = fmaf(p, bflo(u.y), a2); a3 = fmaf(p, bfhi(u.y), a3);
    a4 = fmaf(p, bflo(u.z), a4); a5 = fmaf(p, bfhi(u.z), a5);
    a6 = fmaf(p, bflo(u.w), a6); a7 = fmaf(p, bfhi(u.w), a7);
  }
  #pragma unroll
  for (int mask = 16; mask < 64; mask <<= 1) {
    a0 += __shfl_xor(a0, mask); a1 += __shfl_xor(a1, mask);
    a2 += __shfl_xor(a2, mask); a3 += __shfl_xor(a3, mask);
    a4 += __shfl_xor(a4, mask); a5 += __shfl_xor(a5, mask);
    a6 += __shfl_xor(a6, mask); a7 += __shfl_xor(a7, mask);
  }
  if (lane < 16) {
    float4 b0 = *(const float4*)&bias[cl * 8];
    float4 b1 = *(const float4*)&bias[cl * 8 + 4];
    float v0 = fmaf(a0, invp, b0.x), v1 = fmaf(a1, invp, b0.y);
    float v2 = fmaf(a2, invp, b0.z), v3 = fmaf(a3, invp, b0.w);
    float v4 = fmaf(a4, invp, b1.x), v5 = fmaf(a5, invp, b1.y);
    float v6 = fmaf(a6, invp, b1.z), v7 = fmaf(a7, invp, b1.w);
    v0 = v0 > 0.f ? v0 : expm1f(v0); v1 = v1 > 0.f ? v1 : expm1f(v1);
    v2 = v2 > 0.f ? v2 : expm1f(v2); v3 = v3 > 0.f ? v3 : expm1f(v3);
    v4 = v4 > 0.f ? v4 : expm1f(v4); v5 = v5 > 0.f ? v5 : expm1f(v5);
    v6 = v6 > 0.f ? v6 : expm1f(v6); v7 = v7 > 0.f ? v7 : expm1f(v7);
    uint4 o;
    o.x = (uint32_t)f2bf(v0) | ((uint32_t)f2bf(v1) << 16);
    o.y = (uint32_t)f2bf(v2) | ((uint32_t)f2bf(v3) << 16);
    o.z = (uint32_t)f2bf(v4) | ((uint32_t)f2bf(v5) << 16);
    o.w = (uint32_t)f2bf(v6) | ((uint32_t)f2bf(v7) << 16);
    *(uint4*)&Outb[(size_t)d * 128 + cl * 8] = o;
  }
}

// ================= fused attn+pull (H=1, C=2) for g4 =================
__launch_bounds__(256)
__global__ void fused_gat1_kernel(const int* __restrict__ rowptr, const int* __restrict__ csr,
                                  const float* __restrict__ S, const float* __restrict__ T,
                                  const float* __restrict__ Hm2, const float* __restrict__ bias,
                                  float* __restrict__ galpha, float* __restrict__ Out) {
  int d = (blockIdx.x * 256 + threadIdx.x) >> 6;
  if (d >= NN) return;
  int lane = threadIdx.x & 63;
  int rs = rowptr[d], deg = rowptr[d + 1] - rs;
  float Td = T[d];
  int sn = 0;
  float e = -1e30f;
  if (lane < deg) { sn = csr[rs + lane]; e = lrelu(S[sn] + Td); }
  float m = e;
  for (int l2 = 64 + lane; l2 < deg; l2 += 64) {      // spill (deg>64, rare)
    float e2 = lrelu(S[csr[rs + l2]] + Td);
    galpha[rs + l2] = e2;
    m = fmaxf(m, e2);
  }
  #pragma unroll
  for (int mask = 1; mask < 64; mask <<= 1) m = fmaxf(m, __shfl_xor(m, mask));
  float p = (lane < deg) ? __expf(e - m) : 0.f;
  float sum = p;
  for (int l2 = 64 + lane; l2 < deg; l2 += 64) {
    float p2 = __expf(galpha[rs + l2] - m);
    galpha[rs + l2] = p2;
    sum += p2;
  }
  #pragma unroll
  for (int mask = 1; mask < 64; mask <<= 1) sum += __shfl_xor(sum, mask);
  float inv = 1.f / (sum + 1e-16f);
  float a0 = 0.f, a1 = 0.f;
  if (lane < deg) {
    float2 hv = *(const float2*)&Hm2[(size_t)sn * 2];
    a0 = p * hv.x; a1 = p * hv.y;
  }
  for (int l2 = 64 + lane; l2 < deg; l2 += 64) {
    int sn2 = csr[rs + l2];
    float p2 = galpha[rs + l2];
    float2 hv = *(const float2*)&Hm2[(size_t)sn2 * 2];
    a0 = fmaf(p2, hv.x, a0); a1 = fmaf(p2, hv.y, a1);
  }
  #pragma unroll
  for (int mask = 1; mask < 64; mask <<= 1) {
    a0 += __shfl_xor(a0, mask); a1 += __shfl_xor(a1, mask);
  }
  if (lane == 0) {
    float v0 = fmaf(a0, inv, bias[0]);
    float v1 = fmaf(a1, inv, bias[1]);
    v0 = v0 > 0.f ? v0 : expm1f(v0);
    v1 = v1 > 0.f ? v1 : expm1f(v1);
    float2 o; o.x = v0; o.y = v1;
    *(float2*)&Out[(size_t)d * 2] = o;
  }
}

// ================= pull-based GCN (f32, 4-edge unroll) =================
__launch_bounds__(256)
__global__ void gcn_pull_kernel(const int* __restrict__ rowptr, const int* __restrict__ csr_src,
                                const float* __restrict__ dinv, const float* __restrict__ Hm,
                                const float* __restrict__ bias, float* __restrict__ Out) {
  int d = blockIdx.x * 16 + threadIdx.x / 16;
  if (d >= NN) return;
  int f = threadIdx.x & 15;
  int rs = rowptr[d], re = rowptr[d + 1];
  float acc = 0.f;
  int j = rs;
  for (; j + 4 <= re; j += 4) {
    int s0 = csr_src[j], s1 = csr_src[j + 1], s2 = csr_src[j + 2], s3 = csr_src[j + 3];
    float d0 = dinv[s0], d1 = dinv[s1], d2 = dinv[s2], d3 = dinv[s3];
    float h0 = Hm[(size_t)s0 * 16 + f], h1 = Hm[(size_t)s1 * 16 + f];
    float h2 = Hm[(size_t)s2 * 16 + f], h3 = Hm[(size_t)s3 * 16 + f];
    acc = fmaf(d0, h0, acc); acc = fmaf(d1, h1, acc);
    acc = fmaf(d2, h2, acc); acc = fmaf(d3, h3, acc);
  }
  for (; j < re; ++j) {
    int sn = csr_src[j];
    acc = fmaf(dinv[sn], Hm[(size_t)sn * 16 + f], acc);
  }
  float v = acc * dinv[d] + bias[f];
  Out[(size_t)d * 16 + f] = v > 0.f ? v : expm1f(v);
}

// ---------------- final concat + log_softmax ----------------
__launch_bounds__(256)
__global__ void final_kernel(const float* __restrict__ A, float* __restrict__ Out) {
  int i = blockIdx.x * 256 + threadIdx.x;
  if (i >= HALFN) return;
  float v0 = A[(size_t)i * 2 + 0];
  float v1 = A[(size_t)i * 2 + 1];
  float v2 = A[(size_t)(i + HALFN) * 2 + 0];
  float v3 = A[(size_t)(i + HALFN) * 2 + 1];
  float m = fmaxf(fmaxf(v0, v1), fmaxf(v2, v3));
  float e0 = __expf(v0 - m), e1 = __expf(v1 - m), e2 = __expf(v2 - m), e3 = __expf(v3 - m);
  float l = logf(e0 + e1 + e2 + e3) + m;
  Out[(size_t)i * 4 + 0] = v0 - l;
  Out[(size_t)i * 4 + 1] = v1 - l;
  Out[(size_t)i * 4 + 2] = v2 - l;
  Out[(size_t)i * 4 + 3] = v3 - l;
}

// ---------------- one bf16 GAT layer (H=8, C=16) ----------------
template<int K, bool XBF>
static void run_gat128(const void* Xin, const float* W, const float* aS, const float* aD,
                       const float* bias, const int* rowptr, const int* csr,
                       uint16_t* hbf, uint16_t* outb, float* S, float* T, float* galpha,
                       hipStream_t stream) {
  gemm_bf16_kernel<K, XBF><<<(NN + 63) / 64, 256, 0, stream>>>(Xin, W, hbf, NN);
  score_bf16_kernel<8, 16><<<(NN * 8 + 255) / 256, 256, 0, stream>>>(
      (const uint32_t*)hbf, aS, aD, S, T, NN);
  fused_gat_kernel<<<(NN * 64 + 255) / 256, 256, 0, stream>>>(
      rowptr, csr, S, T, (const uint4*)hbf, bias, galpha, outb);
}

extern "C" void kernel_launch(void* const* d_in, const int* in_sizes, int n_in,
                              void* d_out, int out_size, void* d_ws, size_t ws_size,
                              hipStream_t stream) {
  const float* x     = (const float*)d_in[0];
  const int*   eidx  = (const int*)d_in[1];
  const int*   esrc  = eidx;
  const int*   edst  = eidx + NE;
  const float* gcn_w = (const float*)d_in[2];
  const float* gcn_b = (const float*)d_in[3];

  char* ws = (char*)d_ws;
  uint16_t* bufAb  = (uint16_t*)(ws + 0);            // N*128 bf16 (GAT layer out)
  uint16_t* hbf    = (uint16_t*)(ws + 25600000);     // N*128 bf16 (post-GEMM h)
  float*    bufB   = (float*)   (ws + 51200000);     // N*16 f32 (GCN h / g4 h)
  float*    bufC   = (float*)   (ws + 57600000);     // N*16 f32 (GCN out; later g4 out [N,2])
  float*    Sb     = (float*)   (ws + 64000000);     // N*8
  float*    Tb     = (float*)   (ws + 67200000);     // N*8
  float*    galpha = (float*)   (ws + 70400000);     // ET*8 f32 (spill only)
  int*      rowptr = (int*)     (ws + 124800000);    // NN+1
  int*      cursor = (int*)     (ws + 125200128);    // NN (degrees)
  int*      csr    = (int*)     (ws + 125600128);    // ET
  float*    dinv   = (float*)   (ws + 132400128);    // NN
  int*      bsums  = (int*)     (ws + 132800128);    // ~98
  int*      rank   = (int*)     (ws + 132800640);    // ET

  constexpr int NB_SCAN = (NN + SCB - 1) / SCB;  // 98

  // ---------------- CSR build ----------------
  hipMemsetAsync(cursor, 0, (size_t)NN * 4, stream);
  rank_kernel<<<(ET + 255) / 256, 256, 0, stream>>>(edst, cursor, rank);
  scan1_kernel<<<NB_SCAN, 256, 0, stream>>>(cursor, rowptr, bsums);
  scan2_kernel<<<1, 256, 0, stream>>>(bsums, NB_SCAN);
  scan3_kernel<<<(NN + 256) / 256, 256, 0, stream>>>(rowptr, bsums);
  dinv_kernel<<<(NN + 255) / 256, 256, 0, stream>>>(rowptr, dinv);
  {
    int nch = (ET + CHUNK - 1) / CHUNK;
    scatter_part_kernel<<<nch * RP, 256, 0, stream>>>(esrc, edst, rowptr, rank, csr);
  }

  // ---------------- GCN layer: x[n,128] -> bufC[n,16] ----------------
  {
    constexpr int RT = (256 / (16 / 4)) * 2;  // 128 rows/tile
    int tiles = (NN + RT - 1) / RT;
    if (tiles > 4096) tiles = 4096;
    gemm4_kernel<128, 16><<<tiles, 256, 0, stream>>>(x, gcn_w, bufB, NN);
  }
  gcn_pull_kernel<<<(NN + 15) / 16, 256, 0, stream>>>(rowptr, csr, dinv, bufB, gcn_b, bufC);

  // ---------------- GAT layers 1-3 (bf16 h, fused attn+pull) ----------------
  run_gat128<16, false>(bufC, (const float*)d_in[4], (const float*)d_in[5],
                        (const float*)d_in[6], (const float*)d_in[7],
                        rowptr, csr, hbf, bufAb, Sb, Tb, galpha, stream);
  run_gat128<128, true>(bufAb, (const float*)d_in[8], (const float*)d_in[9],
                        (const float*)d_in[10], (const float*)d_in[11],
                        rowptr, csr, hbf, bufAb, Sb, Tb, galpha, stream);
  run_gat128<128, true>(bufAb, (const float*)d_in[12], (const float*)d_in[13],
                        (const float*)d_in[14], (const float*)d_in[15],
                        rowptr, csr, hbf, bufAb, Sb, Tb, galpha, stream);

  // ---------------- GAT layer 4 (H=1, C=2) ----------------
  {
    int tiles = (NN + 127) / 128;
    if (tiles > 2048) tiles = 2048;
    gemm_s_kernel<128, 2, 128, true><<<tiles, 256, 0, stream>>>(
        bufAb, (const float*)d_in[16], bufB, NN);
    score_kernel<1, 2><<<(NN + 255) / 256, 256, 0, stream>>>(
        bufB, (const float*)d_in[17], (const float*)d_in[18], Sb, Tb, NN);
    fused_gat1_kernel<<<(NN * 64 + 255) / 256, 256, 0, stream>>>(
        rowptr, csr, Sb, Tb, bufB, (const float*)d_in[19], galpha, bufC);
  }

  // ---------------- concat + log_softmax -> d_out [HALFN,4] ----------------
  final_kernel<<<(HALFN + 255) / 256, 256, 0, stream>>>(bufC, (float*)d_out);
}

// Round 6
// 585.400 us; speedup vs baseline: 5.9425x; 1.0996x over previous
//
#include <hip/hip_runtime.h>
#include <cstddef>
#include <cstdint>

#define NN 100000
#define NPAD 100032          // NN rounded to 64 (gemm row tiles)
#define NE 1600000
#define ET (NE + NN)
#define ETP_MAX (ET + 8 * NN)   // padded-CSR capacity
#define HALFN (NN / 2)
#define NEG_SLOPE 0.2f
#define SCB 1024   // elements per scan block
#define DMAX 96    // per-node LDS alpha capacity (multiple of 8; max real degree ~45)
#define RP 8       // scatter regions (one per XCD)
#define RNODES (NN / RP)
#define CHUNK 8192

typedef __attribute__((ext_vector_type(8))) short short8v;   // 8 bf16 (4 VGPRs)
typedef __attribute__((ext_vector_type(4))) float float4v;   // MFMA acc
typedef __attribute__((ext_vector_type(2))) float float2v;

__device__ __forceinline__ float lrelu(float x) { return x > 0.f ? x : NEG_SLOPE * x; }

// ---- bf16 helpers ----
__device__ __forceinline__ uint16_t f2bf(float f) {
  uint32_t u = __float_as_uint(f);
  uint32_t r = u + 0x7fffu + ((u >> 16) & 1u);
  return (uint16_t)(r >> 16);
}
__device__ __forceinline__ float bflo(uint32_t u) { return __uint_as_float(u << 16); }
__device__ __forceinline__ float bfhi(uint32_t u) { return __uint_as_float(u & 0xffff0000u); }

// ---------------- GEMM (f32 in/out), M=16 (GCN) ----------------
template<int K, int M>
__launch_bounds__(256)
__global__ void gemm4_kernel(const float* __restrict__ X, const float* __restrict__ W,
                             float* __restrict__ Y, int n) {
  constexpr int CG = M / 4;
  constexpr int RG = 256 / CG;
  constexpr int RPT = 2;
  constexpr int RT = RG * RPT;
  constexpr int KP = K + 1;
  __shared__ __align__(16) float sW[K * M];
  __shared__ float sX[RT * KP];
  for (int i = threadIdx.x; i < K * M; i += 256) sW[i] = W[i];
  const int jg = threadIdx.x % CG;
  const int rg = threadIdx.x / CG;
  const int r0 = rg * RPT;
  for (int base = blockIdx.x * RT; base < n; base += gridDim.x * RT) {
    __syncthreads();
    const int nrows = (n - base) < RT ? (n - base) : RT;
    for (int i = threadIdx.x; i < nrows * K; i += 256) {
      int r = i / K, c = i - r * K;
      sX[r * KP + c] = X[(size_t)base * K + i];
    }
    __syncthreads();
    float acc[RPT][4];
    #pragma unroll
    for (int rr = 0; rr < RPT; ++rr) acc[rr][0] = acc[rr][1] = acc[rr][2] = acc[rr][3] = 0.f;
    #pragma unroll 4
    for (int k = 0; k < K; ++k) {
      const float4 w = *(const float4*)&sW[k * M + jg * 4];
      #pragma unroll
      for (int rr = 0; rr < RPT; ++rr) {
        const float xv = sX[(r0 + rr) * KP + k];
        acc[rr][0] = fmaf(xv, w.x, acc[rr][0]);
        acc[rr][1] = fmaf(xv, w.y, acc[rr][1]);
        acc[rr][2] = fmaf(xv, w.z, acc[rr][2]);
        acc[rr][3] = fmaf(xv, w.w, acc[rr][3]);
      }
    }
    #pragma unroll
    for (int rr = 0; rr < RPT; ++rr) {
      if (r0 + rr < nrows) {
        float4 o = make_float4(acc[rr][0], acc[rr][1], acc[rr][2], acc[rr][3]);
        *(float4*)&Y[(size_t)(base + r0 + rr) * M + jg * 4] = o;
      }
    }
  }
}

// ---------------- W pack into B-fragment order (bf16, zero-pad K) ----------------
// B[k][n] lane layout for mfma_f32_16x16x32_bf16: n = lane&15, k = (lane>>4)*8 + j.
template<int KB>  // KB = K32 blocks
__launch_bounds__(256)
__global__ void wpack_kernel(const float* __restrict__ W, uint16_t* __restrict__ wp,
                             int Kreal) {
  int tid = blockIdx.x * 256 + threadIdx.x;
  if (tid >= KB * 8 * 64) return;
  int lane = tid & 63;
  int ctkb = tid >> 6;
  int kb = ctkb % KB, ct = ctkb / KB;
  int nc = ct * 16 + (lane & 15);
  int k0 = kb * 32 + (lane >> 4) * 8;
  ushort4 o0, o1;
  uint16_t v[8];
  #pragma unroll
  for (int j = 0; j < 8; ++j) {
    int k = k0 + j;
    v[j] = (k < Kreal) ? f2bf(W[(size_t)k * 128 + nc]) : (uint16_t)0;
  }
  o0.x = v[0]; o0.y = v[1]; o0.z = v[2]; o0.w = v[3];
  o1.x = v[4]; o1.y = v[5]; o1.z = v[6]; o1.w = v[7];
  *(ushort4*)&wp[(size_t)tid * 8] = o0;
  *(ushort4*)&wp[(size_t)tid * 8 + 4] = o1;
}

// ---------------- MFMA GEMM: Y[n,128] = X[n,K] @ W, bf16 in/out ----------------
template<int KB, int XS>   // KB: K/32 blocks; XS: X row stride in bf16 elems
__launch_bounds__(256)
__global__ void gemm_mfma_kernel(const uint16_t* __restrict__ X,
                                 const uint16_t* __restrict__ wp,
                                 uint16_t* __restrict__ Y, int n) {
  __shared__ float sC[4][16 * 136];    // 136-stride: 16B-aligned rows, spread banks
  const int wv = threadIdx.x >> 6;
  const int lane = threadIdx.x & 63;
  const int rowbase = blockIdx.x * 64 + wv * 16;
  int arow = rowbase + (lane & 15);
  if (arow >= n) arow = n - 1;                    // clamp: finite garbage in pad rows
  const uint16_t* xp = X + (size_t)arow * XS + ((lane >> 4) * 8);
  short8v a[KB];
  #pragma unroll
  for (int kb = 0; kb < KB; ++kb) a[kb] = *(const short8v*)(xp + kb * 32);
  #pragma unroll
  for (int ct = 0; ct < 8; ++ct) {
    float4v acc = {0.f, 0.f, 0.f, 0.f};
    #pragma unroll
    for (int kb = 0; kb < KB; ++kb) {
      short8v b = *(const short8v*)&wp[(size_t)((ct * KB + kb) * 64 + lane) * 8];
      acc = __builtin_amdgcn_mfma_f32_16x16x32_bf16(a[kb], b, acc, 0, 0, 0);
    }
    // D[row=(lane>>4)*4+r][col=ct*16+(lane&15)]
    #pragma unroll
    for (int r = 0; r < 4; ++r)
      sC[wv][((lane >> 4) * 4 + r) * 136 + ct * 16 + (lane & 15)] = acc[r];
  }
  // pack & store (wave-local; compiler inserts lgkmcnt for LDS deps)
  #pragma unroll
  for (int t = 0; t < 4; ++t) {
    int idx = t * 64 + lane;         // 256 uint4-chunks = 16 rows x 16 chunks
    int row = idx >> 4;
    int c8 = idx & 15;
    const float* pr = &sC[wv][row * 136 + c8 * 8];
    float4 lo = *(const float4*)pr;
    float4 hi = *(const float4*)(pr + 4);
    uint4 o;
    o.x = (uint32_t)f2bf(lo.x) | ((uint32_t)f2bf(lo.y) << 16);
    o.y = (uint32_t)f2bf(lo.z) | ((uint32_t)f2bf(lo.w) << 16);
    o.z = (uint32_t)f2bf(hi.x) | ((uint32_t)f2bf(hi.y) << 16);
    o.w = (uint32_t)f2bf(hi.z) | ((uint32_t)f2bf(hi.w) << 16);
    *(uint4*)&Y[(size_t)(rowbase + row) * 128 + c8 * 8] = o;
  }
}

// ---------------- GEMM, small M (M=2), bf16 input (g4) ----------------
template<int K, int M, int ROWS>
__launch_bounds__(256)
__global__ void gemm_s_kernel(const uint16_t* __restrict__ Xb, const float* __restrict__ W,
                              float* __restrict__ Y, int n) {
  constexpr int KP = K + 1;
  __shared__ float sW[K * M];
  __shared__ float sX[ROWS * KP];
  for (int i = threadIdx.x; i < K * M; i += 256) sW[i] = W[i];
  for (int base = blockIdx.x * ROWS; base < n; base += gridDim.x * ROWS) {
    __syncthreads();
    const int nrows = (n - base) < ROWS ? (n - base) : ROWS;
    for (int i = threadIdx.x; i < nrows * (K / 4); i += 256) {
      int r = i / (K / 4), c = i - r * (K / 4);
      uint2 u = *(const uint2*)&Xb[(size_t)(base + r) * K + c * 4];
      sX[r * KP + c * 4 + 0] = bflo(u.x);
      sX[r * KP + c * 4 + 1] = bfhi(u.x);
      sX[r * KP + c * 4 + 2] = bflo(u.y);
      sX[r * KP + c * 4 + 3] = bfhi(u.y);
    }
    __syncthreads();
    for (int o = threadIdx.x; o < nrows * M; o += 256) {
      int r = o / M, j = o - r * M;
      float a = 0.f;
      #pragma unroll
      for (int k = 0; k < K; ++k) a = fmaf(sX[r * KP + k], sW[k * M + j], a);
      Y[(size_t)(base + r) * M + j] = a;
    }
  }
}

// ---------------- scores from bf16 h (+pad row: S=-1e30) ----------------
template<int H, int C>
__launch_bounds__(256)
__global__ void score_bf16_kernel(const uint32_t* __restrict__ Hm,
                                  const float* __restrict__ aS, const float* __restrict__ aD,
                                  float* __restrict__ S, float* __restrict__ T, int n) {
  int idx = blockIdx.x * 256 + threadIdx.x;
  int tot = n * H;
  if (idx >= tot + H) return;
  if (idx >= tot) { S[idx] = -1e30f; T[idx] = 0.f; return; }
  int h = idx & (H - 1);
  const uint32_t* hp = Hm + (size_t)idx * (C / 2);
  float s = 0.f, t = 0.f;
  #pragma unroll
  for (int c2 = 0; c2 < C / 2; ++c2) {
    uint32_t u = hp[c2];
    float v0 = bflo(u), v1 = bfhi(u);
    s = fmaf(v0, aS[h * C + 2 * c2], s);
    s = fmaf(v1, aS[h * C + 2 * c2 + 1], s);
    t = fmaf(v0, aD[h * C + 2 * c2], t);
    t = fmaf(v1, aD[h * C + 2 * c2 + 1], t);
  }
  S[idx] = s;
  T[idx] = t;
}

// ---------------- scores f32 (g4, H=1) +pad ----------------
template<int H, int C>
__launch_bounds__(256)
__global__ void score_kernel(const float* __restrict__ Hm,
                             const float* __restrict__ aS, const float* __restrict__ aD,
                             float* __restrict__ S, float* __restrict__ T, int n) {
  int idx = blockIdx.x * 256 + threadIdx.x;
  int tot = n * H;
  if (idx >= tot + H) return;
  if (idx >= tot) { S[idx] = -1e30f; T[idx] = 0.f; return; }
  int h = idx & (H - 1);
  const float* hp = Hm + (size_t)idx * C;
  float s = 0.f, t = 0.f;
  #pragma unroll
  for (int c = 0; c < C; ++c) {
    float v = hp[c];
    s = fmaf(v, aS[h * C + c], s);
    t = fmaf(v, aD[h * C + c], t);
  }
  S[idx] = s;
  T[idx] = t;
}

// ================= CSR build (rows padded to multiples of 8) =================
__launch_bounds__(256)
__global__ void rank_kernel(const int* __restrict__ edst, int* __restrict__ cursor,
                            int* __restrict__ rank) {
  int e = blockIdx.x * 256 + threadIdx.x;
  if (e >= ET) return;
  int dn = e < NE ? edst[e] : e - NE;
  rank[e] = atomicAdd(&cursor[dn], 1);
}

__device__ __forceinline__ int pad8(int d) { return (d + 7) & ~7; }

__launch_bounds__(256)
__global__ void scan1_kernel(const int* __restrict__ degi, int* __restrict__ rowptr,
                             int* __restrict__ bsums) {
  __shared__ int sd[256];
  int t = threadIdx.x;
  int base = blockIdx.x * SCB + t * 4;
  int v0 = base + 0 < NN ? pad8(degi[base + 0]) : 0;
  int v1 = base + 1 < NN ? pad8(degi[base + 1]) : 0;
  int v2 = base + 2 < NN ? pad8(degi[base + 2]) : 0;
  int v3 = base + 3 < NN ? pad8(degi[base + 3]) : 0;
  int s = v0 + v1 + v2 + v3;
  sd[t] = s;
  __syncthreads();
  for (int off = 1; off < 256; off <<= 1) {
    int x = (t >= off) ? sd[t - off] : 0;
    __syncthreads();
    sd[t] += x;
    __syncthreads();
  }
  int excl = sd[t] - s;
  if (t == 255) bsums[blockIdx.x] = sd[255];
  if (base + 0 < NN) rowptr[base + 0] = excl;
  excl += v0;
  if (base + 1 < NN) rowptr[base + 1] = excl;
  excl += v1;
  if (base + 2 < NN) rowptr[base + 2] = excl;
  excl += v2;
  if (base + 3 < NN) rowptr[base + 3] = excl;
}

__launch_bounds__(256)
__global__ void scan2_kernel(int* __restrict__ bsums, int nb) {
  __shared__ int sd[256];
  int t = threadIdx.x;
  int v = t < nb ? bsums[t] : 0;
  sd[t] = v;
  __syncthreads();
  for (int off = 1; off < 256; off <<= 1) {
    int x = (t >= off) ? sd[t - off] : 0;
    __syncthreads();
    sd[t] += x;
    __syncthreads();
  }
  if (t < nb) bsums[t] = sd[t] - v;       // exclusive
  if (t == nb - 1) bsums[nb] = sd[t];     // total (padded ET)
}

__launch_bounds__(256)
__global__ void scan3_kernel(int* __restrict__ rowptr, const int* __restrict__ bsums, int nb) {
  int i = blockIdx.x * 256 + threadIdx.x;
  if (i < NN) rowptr[i] += bsums[i / SCB];
  if (i == 0) rowptr[NN] = bsums[nb];
}

__launch_bounds__(256)
__global__ void dinv_kernel(const int* __restrict__ deg, float* __restrict__ dinv) {
  int i = blockIdx.x * 256 + threadIdx.x;
  if (i > NN) return;
  if (i == NN) { dinv[i] = 0.f; return; }     // dummy row contributes 0
  int d = deg[i];
  dinv[i] = d > 0 ? rsqrtf((float)d) : 0.f;
}

__launch_bounds__(256)
__global__ void csr_fill_kernel(int* __restrict__ csr) {
  int i = blockIdx.x * 256 + threadIdx.x;
  if (i < ETP_MAX) csr[i] = NN;   // dummy src
}

__launch_bounds__(256)
__global__ void scatter_part_kernel(const int* __restrict__ esrc, const int* __restrict__ edst,
                                    const int* __restrict__ rowptr, const int* __restrict__ rank,
                                    int* __restrict__ csr_src) {
  int p = blockIdx.x & (RP - 1);
  int c = blockIdx.x >> 3;
  int lo = p * RNODES, hi = lo + RNODES;
  int e0 = c * CHUNK;
  int e1 = e0 + CHUNK < ET ? e0 + CHUNK : ET;
  for (int e = e0 + threadIdx.x; e < e1; e += 256) {
    int dn = e < NE ? edst[e] : e - NE;
    if (dn >= lo && dn < hi) {
      int sn = e < NE ? esrc[e] : e - NE;
      csr_src[rowptr[dn] + rank[e]] = sn;
    }
  }
}

// ================= fused attn+pull (H=8, C=16), padded rows =================
__launch_bounds__(256)
__global__ void fused_gat_kernel(const int* __restrict__ rowptr, const int* __restrict__ csr,
                                 const float* __restrict__ S, const float* __restrict__ T,
                                 const uint16_t* __restrict__ Hm, const float* __restrict__ bias,
                                 float* __restrict__ galpha, uint16_t* __restrict__ Outb) {
  __shared__ float lds_p[4][DMAX * 9];
  __shared__ int   lds_c[4][DMAX];
  const int wv = threadIdx.x >> 6;
  const int lane = threadIdx.x & 63;
  const int d = (blockIdx.x * 256 + threadIdx.x) >> 6;
  if (d >= NN) return;
  const int rs = rowptr[d];
  const int deg = rowptr[d + 1] - rs;          // multiple of 8
  const int degL = deg < DMAX ? deg : DMAX;    // multiple of 8 (DMAX=96)
  const char* sb = (const char*)S;
  const char* hb = (const char*)Hm;
  // ---- P1a: e into LDS, running max (uniform loops) ----
  const int h = lane & 7, g = lane >> 3;
  const float Th = T[(size_t)d * 8 + h];
  float m = -1e30f;
  for (int l = g; l < degL; l += 8) {
    int sn = csr[rs + l];
    float sv = *(const float*)(sb + (((uint32_t)sn << 5) + (h << 2)));
    float e = lrelu(sv + Th);
    lds_p[wv][l * 9 + h] = e;
    if (h == 0) lds_c[wv][l] = sn;
    m = fmaxf(m, e);
  }
  for (int l = DMAX + g; l < deg; l += 8) {    // spill (never on this graph)
    int sn = csr[rs + l];
    float e = lrelu(*(const float*)(sb + (((uint32_t)sn << 5) + (h << 2))) + Th);
    galpha[(size_t)(rs + l) * 8 + h] = e;
    m = fmaxf(m, e);
  }
  #pragma unroll
  for (int mask = 8; mask < 64; mask <<= 1) m = fmaxf(m, __shfl_xor(m, mask));
  // ---- P1b: p = exp(e-m), sum ----
  float sum = 0.f;
  for (int l = g; l < degL; l += 8) {
    float p = __expf(lds_p[wv][l * 9 + h] - m);
    lds_p[wv][l * 9 + h] = p;
    sum += p;
  }
  for (int l = DMAX + g; l < deg; l += 8) {
    float p = __expf(galpha[(size_t)(rs + l) * 8 + h] - m);
    galpha[(size_t)(rs + l) * 8 + h] = p;
    sum += p;
  }
  #pragma unroll
  for (int mask = 8; mask < 64; mask <<= 1) sum += __shfl_xor(sum, mask);
  const float inv = 1.f / (sum + 1e-16f);
  // ---- P2: lane = (edge-group eg 0..3, chan-block cl 0..15), uniform ----
  const int eg = lane >> 4;
  const int cl = lane & 15;
  const int hp = cl >> 1;
  const float invp = __shfl(inv, hp);
  float2v A0 = {0.f, 0.f}, A1 = {0.f, 0.f}, A2 = {0.f, 0.f}, A3 = {0.f, 0.f};
  const uint32_t clo = (uint32_t)(cl << 4);
  #pragma unroll 2
  for (int l0 = 0; l0 < degL; l0 += 4) {
    int lc = l0 + eg;
    int sn = lds_c[wv][lc];
    float p = lds_p[wv][lc * 9 + hp];
    float2v pp = {p, p};
    uint4 u = *(const uint4*)(hb + (((uint32_t)sn << 8) + clo));
    float2v h0 = {bflo(u.x), bfhi(u.x)};
    float2v h1 = {bflo(u.y), bfhi(u.y)};
    float2v h2 = {bflo(u.z), bfhi(u.z)};
    float2v h3 = {bflo(u.w), bfhi(u.w)};
    A0 = pp * h0 + A0;
    A1 = pp * h1 + A1;
    A2 = pp * h2 + A2;
    A3 = pp * h3 + A3;
  }
  for (int l0 = DMAX; l0 < deg; l0 += 4) {     // spill
    int lc = l0 + eg;
    int sn = csr[rs + lc];
    float p = galpha[(size_t)(rs + lc) * 8 + hp];
    float2v pp = {p, p};
    uint4 u = *(const uint4*)(hb + (((uint32_t)sn << 8) + clo));
    float2v h0 = {bflo(u.x), bfhi(u.x)};
    float2v h1 = {bflo(u.y), bfhi(u.y)};
    float2v h2 = {bflo(u.z), bfhi(u.z)};
    float2v h3 = {bflo(u.w), bfhi(u.w)};
    A0 = pp * h0 + A0;
    A1 = pp * h1 + A1;
    A2 = pp * h2 + A2;
    A3 = pp * h3 + A3;
  }
  #pragma unroll
  for (int mask = 16; mask < 64; mask <<= 1) {
    A0.x += __shfl_xor(A0.x, mask); A0.y += __shfl_xor(A0.y, mask);
    A1.x += __shfl_xor(A1.x, mask); A1.y += __shfl_xor(A1.y, mask);
    A2.x += __shfl_xor(A2.x, mask); A2.y += __shfl_xor(A2.y, mask);
    A3.x += __shfl_xor(A3.x, mask); A3.y += __shfl_xor(A3.y, mask);
  }
  if (lane < 16) {
    float4 b0 = *(const float4*)&bias[cl * 8];
    float4 b1 = *(const float4*)&bias[cl * 8 + 4];
    float v0 = fmaf(A0.x, invp, b0.x), v1 = fmaf(A0.y, invp, b0.y);
    float v2 = fmaf(A1.x, invp, b0.z), v3 = fmaf(A1.y, invp, b0.w);
    float v4 = fmaf(A2.x, invp, b1.x), v5 = fmaf(A2.y, invp, b1.y);
    float v6 = fmaf(A3.x, invp, b1.z), v7 = fmaf(A3.y, invp, b1.w);
    v0 = v0 > 0.f ? v0 : expm1f(v0); v1 = v1 > 0.f ? v1 : expm1f(v1);
    v2 = v2 > 0.f ? v2 : expm1f(v2); v3 = v3 > 0.f ? v3 : expm1f(v3);
    v4 = v4 > 0.f ? v4 : expm1f(v4); v5 = v5 > 0.f ? v5 : expm1f(v5);
    v6 = v6 > 0.f ? v6 : expm1f(v6); v7 = v7 > 0.f ? v7 : expm1f(v7);
    uint4 o;
    o.x = (uint32_t)f2bf(v0) | ((uint32_t)f2bf(v1) << 16);
    o.y = (uint32_t)f2bf(v2) | ((uint32_t)f2bf(v3) << 16);
    o.z = (uint32_t)f2bf(v4) | ((uint32_t)f2bf(v5) << 16);
    o.w = (uint32_t)f2bf(v6) | ((uint32_t)f2bf(v7) << 16);
    *(uint4*)&Outb[(size_t)d * 128 + cl * 8] = o;
  }
}

// ================= fused attn+pull (H=1, C=2) for g4, padded rows =============
__launch_bounds__(256)
__global__ void fused_gat1_kernel(const int* __restrict__ rowptr, const int* __restrict__ csr,
                                  const float* __restrict__ S, const float* __restrict__ T,
                                  const float* __restrict__ Hm2, const float* __restrict__ bias,
                                  float* __restrict__ galpha, float* __restrict__ Out) {
  int d = (blockIdx.x * 256 + threadIdx.x) >> 6;
  if (d >= NN) return;
  int lane = threadIdx.x & 63;
  int rs = rowptr[d], deg = rowptr[d + 1] - rs;
  float Td = T[d];
  int sn = 0;
  float e = -1e30f;
  if (lane < deg) { sn = csr[rs + lane]; e = lrelu(S[sn] + Td); }
  float m = e;
  for (int l2 = 64 + lane; l2 < deg; l2 += 64) {
    float e2 = lrelu(S[csr[rs + l2]] + Td);
    galpha[rs + l2] = e2;
    m = fmaxf(m, e2);
  }
  #pragma unroll
  for (int mask = 1; mask < 64; mask <<= 1) m = fmaxf(m, __shfl_xor(m, mask));
  float p = (lane < deg) ? __expf(e - m) : 0.f;
  float sum = p;
  for (int l2 = 64 + lane; l2 < deg; l2 += 64) {
    float p2 = __expf(galpha[rs + l2] - m);
    galpha[rs + l2] = p2;
    sum += p2;
  }
  #pragma unroll
  for (int mask = 1; mask < 64; mask <<= 1) sum += __shfl_xor(sum, mask);
  float inv = 1.f / (sum + 1e-16f);
  float a0 = 0.f, a1 = 0.f;
  if (lane < deg) {
    float2 hv = *(const float2*)&Hm2[(size_t)sn * 2];
    a0 = p * hv.x; a1 = p * hv.y;
  }
  for (int l2 = 64 + lane; l2 < deg; l2 += 64) {
    int sn2 = csr[rs + l2];
    float p2 = galpha[rs + l2];
    float2 hv = *(const float2*)&Hm2[(size_t)sn2 * 2];
    a0 = fmaf(p2, hv.x, a0); a1 = fmaf(p2, hv.y, a1);
  }
  #pragma unroll
  for (int mask = 1; mask < 64; mask <<= 1) {
    a0 += __shfl_xor(a0, mask); a1 += __shfl_xor(a1, mask);
  }
  if (lane == 0) {
    float v0 = fmaf(a0, inv, bias[0]);
    float v1 = fmaf(a1, inv, bias[1]);
    v0 = v0 > 0.f ? v0 : expm1f(v0);
    v1 = v1 > 0.f ? v1 : expm1f(v1);
    float2 o; o.x = v0; o.y = v1;
    *(float2*)&Out[(size_t)d * 2] = o;
  }
}

// ================= GCN pull (padded rows; dinv[NN]=0 kills dummies) ============
// writes bf16 out [N][32] with cols 16..31 zero (g1 MFMA input, K padded to 32)
__launch_bounds__(256)
__global__ void gcn_pull_kernel(const int* __restrict__ rowptr, const int* __restrict__ csr_src,
                                const float* __restrict__ dinv, const float* __restrict__ Hm,
                                const float* __restrict__ bias, uint16_t* __restrict__ Outb) {
  int d = blockIdx.x * 16 + threadIdx.x / 16;
  if (d >= NN) return;
  int f = threadIdx.x & 15;
  int rs = rowptr[d], re = rowptr[d + 1];
  float acc = 0.f;
  int j = rs;
  for (; j + 4 <= re; j += 4) {
    int s0 = csr_src[j], s1 = csr_src[j + 1], s2 = csr_src[j + 2], s3 = csr_src[j + 3];
    float d0 = dinv[s0], d1 = dinv[s1], d2 = dinv[s2], d3 = dinv[s3];
    float h0 = Hm[(size_t)s0 * 16 + f], h1 = Hm[(size_t)s1 * 16 + f];
    float h2 = Hm[(size_t)s2 * 16 + f], h3 = Hm[(size_t)s3 * 16 + f];
    acc = fmaf(d0, h0, acc); acc = fmaf(d1, h1, acc);
    acc = fmaf(d2, h2, acc); acc = fmaf(d3, h3, acc);
  }
  for (; j < re; ++j) {
    int sn = csr_src[j];
    acc = fmaf(dinv[sn], Hm[(size_t)sn * 16 + f], acc);
  }
  float v = acc * dinv[d] + bias[f];
  v = v > 0.f ? v : expm1f(v);
  Outb[(size_t)d * 32 + f] = f2bf(v);
  Outb[(size_t)d * 32 + 16 + f] = 0;
}

// ---------------- final concat + log_softmax ----------------
__launch_bounds__(256)
__global__ void final_kernel(const float* __restrict__ A, float* __restrict__ Out) {
  int i = blockIdx.x * 256 + threadIdx.x;
  if (i >= HALFN) return;
  float v0 = A[(size_t)i * 2 + 0];
  float v1 = A[(size_t)i * 2 + 1];
  float v2 = A[(size_t)(i + HALFN) * 2 + 0];
  float v3 = A[(size_t)(i + HALFN) * 2 + 1];
  float m = fmaxf(fmaxf(v0, v1), fmaxf(v2, v3));
  float e0 = __expf(v0 - m), e1 = __expf(v1 - m), e2 = __expf(v2 - m), e3 = __expf(v3 - m);
  float l = logf(e0 + e1 + e2 + e3) + m;
  Out[(size_t)i * 4 + 0] = v0 - l;
  Out[(size_t)i * 4 + 1] = v1 - l;
  Out[(size_t)i * 4 + 2] = v2 - l;
  Out[(size_t)i * 4 + 3] = v3 - l;
}

extern "C" void kernel_launch(void* const* d_in, const int* in_sizes, int n_in,
                              void* d_out, int out_size, void* d_ws, size_t ws_size,
                              hipStream_t stream) {
  const float* x     = (const float*)d_in[0];
  const int*   eidx  = (const int*)d_in[1];
  const int*   esrc  = eidx;
  const int*   edst  = eidx + NE;
  const float* gcn_w = (const float*)d_in[2];
  const float* gcn_b = (const float*)d_in[3];

  char* ws = (char*)d_ws;
  uint16_t* hbf    = (uint16_t*)(ws + 0);            // [NPAD][128] bf16 (post-GEMM h)
  uint16_t* bufAb  = (uint16_t*)(ws + 25700000);     // [NPAD][128] bf16 (GAT layer out)
  uint16_t* gcnHbf = (uint16_t*)(ws + 51400000);     // [NN][32] bf16 (g1 X, K-padded)
  float*    bufB   = (float*)   (ws + 57900000);     // [NN+1][16] f32 (GCN h) / g4 h [NN+1][2]
  float*    bufC   = (float*)   (ws + 64400000);     // [NN][2] f32 (g4 out)
  float*    Sb     = (float*)   (ws + 65300000);     // NN*8+8
  float*    Tb     = (float*)   (ws + 68600000);     // NN*8+8
  float*    galpha = (float*)   (ws + 71900000);     // ETP_MAX*8 (spill only)
  int*      rowptr = (int*)     (ws + 151900000);    // NN+1 (padded CSR)
  int*      cursor = (int*)     (ws + 152300008);    // NN (real degrees)
  int*      csr    = (int*)     (ws + 152700008);    // ETP_MAX
  float*    dinv   = (float*)   (ws + 162700008);    // NN+1
  int*      bsums  = (int*)     (ws + 163100016);    // NB+1
  int*      rank   = (int*)     (ws + 163100528);    // ET
  uint16_t* wpck   = (uint16_t*)(ws + 169900528);    // 32KB (per-layer B-fragments)

  constexpr int NB_SCAN = (NN + SCB - 1) / SCB;  // 98

  // ---------------- CSR build (padded rows) ----------------
  hipMemsetAsync(cursor, 0, (size_t)NN * 4, stream);
  rank_kernel<<<(ET + 255) / 256, 256, 0, stream>>>(edst, cursor, rank);
  scan1_kernel<<<NB_SCAN, 256, 0, stream>>>(cursor, rowptr, bsums);
  scan2_kernel<<<1, 256, 0, stream>>>(bsums, NB_SCAN);
  scan3_kernel<<<(NN + 256) / 256, 256, 0, stream>>>(rowptr, bsums, NB_SCAN);
  dinv_kernel<<<(NN + 256) / 256, 256, 0, stream>>>(cursor, dinv);
  csr_fill_kernel<<<(ETP_MAX + 255) / 256, 256, 0, stream>>>(csr);
  {
    int nch = (ET + CHUNK - 1) / CHUNK;
    scatter_part_kernel<<<nch * RP, 256, 0, stream>>>(esrc, edst, rowptr, rank, csr);
  }

  // ---------------- GCN: x[n,128] -> gcnHbf[n,32] bf16 ----------------
  {
    int tiles = (NN + 127) / 128;
    if (tiles > 4096) tiles = 4096;
    gemm4_kernel<128, 16><<<tiles, 256, 0, stream>>>(x, gcn_w, bufB, NN);
  }
  gcn_pull_kernel<<<(NN + 15) / 16, 256, 0, stream>>>(rowptr, csr, dinv, bufB, gcn_b, gcnHbf);

  // ---------------- GAT g1 (K=16->32, MFMA) ----------------
  wpack_kernel<1><<<2, 256, 0, stream>>>((const float*)d_in[4], wpck, 16);
  gemm_mfma_kernel<1, 32><<<NPAD / 64, 256, 0, stream>>>(gcnHbf, wpck, hbf, NN);
  score_bf16_kernel<8, 16><<<(NN * 8 + 8 + 255) / 256, 256, 0, stream>>>(
      (const uint32_t*)hbf, (const float*)d_in[5], (const float*)d_in[6], Sb, Tb, NN);
  fused_gat_kernel<<<(NN * 64 + 255) / 256, 256, 0, stream>>>(
      rowptr, csr, Sb, Tb, hbf, (const float*)d_in[7], galpha, bufAb);

  // ---------------- GAT g2 (K=128, MFMA) ----------------
  wpack_kernel<4><<<8, 256, 0, stream>>>((const float*)d_in[8], wpck, 128);
  gemm_mfma_kernel<4, 128><<<NPAD / 64, 256, 0, stream>>>(bufAb, wpck, hbf, NN);
  score_bf16_kernel<8, 16><<<(NN * 8 + 8 + 255) / 256, 256, 0, stream>>>(
      (const uint32_t*)hbf, (const float*)d_in[9], (const float*)d_in[10], Sb, Tb, NN);
  fused_gat_kernel<<<(NN * 64 + 255) / 256, 256, 0, stream>>>(
      rowptr, csr, Sb, Tb, hbf, (const float*)d_in[11], galpha, bufAb);

  // ---------------- GAT g3 (K=128, MFMA) ----------------
  wpack_kernel<4><<<8, 256, 0, stream>>>((const float*)d_in[12], wpck, 128);
  gemm_mfma_kernel<4, 128><<<NPAD / 64, 256, 0, stream>>>(bufAb, wpck, hbf, NN);
  score_bf16_kernel<8, 16><<<(NN * 8 + 8 + 255) / 256, 256, 0, stream>>>(
      (const uint32_t*)hbf, (const float*)d_in[13], (const float*)d_in[14], Sb, Tb, NN);
  fused_gat_kernel<<<(NN * 64 + 255) / 256, 256, 0, stream>>>(
      rowptr, csr, Sb, Tb, hbf, (const float*)d_in[15], galpha, bufAb);

  // ---------------- GAT g4 (H=1, C=2) ----------------
  {
    int tiles = (NN + 127) / 128;
    if (tiles > 2048) tiles = 2048;
    gemm_s_kernel<128, 2, 128><<<tiles, 256, 0, stream>>>(
        bufAb, (const float*)d_in[16], bufB, NN);
    score_kernel<1, 2><<<(NN + 1 + 255) / 256, 256, 0, stream>>>(
        bufB, (const float*)d_in[17], (const float*)d_in[18], Sb, Tb, NN);
    fused_gat1_kernel<<<(NN * 64 + 255) / 256, 256, 0, stream>>>(
        rowptr, csr, Sb, Tb, bufB, (const float*)d_in[19], galpha, bufC);
  }

  // ---------------- concat + log_softmax -> d_out [HALFN,4] ----------------
  final_kernel<<<(HALFN + 255) / 256, 256, 0, stream>>>(bufC, (float*)d_out);
}